// Round 10
// baseline (2870.227 us; speedup 1.0000x reference)
//
#include <hip/hip_runtime.h>
#include <math.h>

// ---------------------------------------------------------------------------
// PINN beam loss via forward-mode bivariate jets (v10: v9 + packed fp32 FMA).
// Jet of f(z + t*(1,1) + s*(1,0)):  y[k]=coeff t^k, z[k]=coeff t^k s.
// Layer-1: pre-act = p0 + d*t + wx*s  =>  z[k] = (k+1)*(wx/d)*y[k+1] exactly.
//
// Jets live as (y_c, z_c) float2 pairs -> inner loops use v_pk_fma_f32
// (__builtin_elementwise_fma on ext_vector float2; 2x fp32 FMA/instr, exact).
// Weights are pre-duplicated (w,w) in the permuted arrays so the packed
// multiplier needs no per-k splat movs. TYPE0 inner k: 72 -> 40 VALU ops.
// Mapping unchanged from v9: 1-wave blocks, 4 samples/wave, 16 lanes/sample,
// stride-16 output ownership, fully-unrolled pass loop (rule #20).
// ---------------------------------------------------------------------------

#define SSTR 648              // per-sample LDS float stride (64*10 + 8 skew)
#define OFF_W2 49152          // ws float offset of W2perm2 [512][16][8][2]
#define OFF_W3 180224         // ws float offset of W3perm2 [128][16][4][2]

typedef float f32x2 __attribute__((ext_vector_type(2)));
typedef float f32x4 __attribute__((ext_vector_type(4)));

__device__ __forceinline__ f32x2 pkfma(f32x2 a, f32x2 b, f32x2 c) {
    return __builtin_elementwise_fma(a, b, c);   // -> v_pk_fma_f32
}

__device__ __forceinline__ float fast_tanh(float x) {
    float ax = fabsf(x);
    float e  = __expf(-2.0f * ax);
    float y  = (1.0f - e) * __builtin_amdgcn_rcpf(1.0f + e);
    return copysignf(y, x);
}

template<int NA, int NB>
__device__ __forceinline__ void tanh_jet(const float (&p)[NA], const float (&q)[NB],
                                         float (&y)[NA], float (&r)[NB]) {
    constexpr int NU = ((NA - 1) > NB ? (NA - 1) : NB);
    float u[NU];
    y[0] = fast_tanh(p[0]);
    u[0] = fmaf(-y[0], y[0], 1.0f);
    if constexpr (NA >= 2) y[1] = u[0] * p[1];
    if constexpr (NU >= 2) u[1] = -2.0f * y[0] * y[1];
    if constexpr (NA >= 3) y[2] = fmaf(u[0], p[2], 0.5f * u[1] * p[1]);
    if constexpr (NU >= 3) u[2] = -fmaf(2.0f * y[0], y[2], y[1] * y[1]);
    if constexpr (NA >= 4) y[3] = fmaf(u[0], p[3], fmaf((2.0f/3.0f) * u[1], p[2],
                                       (1.0f/3.0f) * u[2] * p[1]));
    if constexpr (NU >= 4) u[3] = -2.0f * fmaf(y[0], y[3], y[1] * y[2]);
    if constexpr (NA >= 5) y[4] = fmaf(u[0], p[4], fmaf(0.75f * u[1], p[3],
                                       fmaf(0.5f * u[2], p[2], 0.25f * u[3] * p[1])));
    #pragma unroll
    for (int k = 0; k < NB; ++k) {
        float s = 0.0f;
        #pragma unroll
        for (int j = 0; j <= k; ++j) s = fmaf(u[j], q[k - j], s);
        r[k] = s;
    }
}

// Duplicated + permuted weights for packed FMA with stride-16 lane ownership:
//   W2perm2[k][g][j][d] = W2[k*128 + g + 16*j]   (k<512, g<16, j<8, d<2)
//   W3perm2[k][g][j][d] = W3[k*64  + g + 16*j]   (k<128, g<16, j<4, d<2)
__global__ __launch_bounds__(256)
void pinn_prep(const float* __restrict__ W2, const float* __restrict__ W3,
               float* __restrict__ ws)
{
    const int i = blockIdx.x * 256 + threadIdx.x;
    if (i < 131072) {
        const int k = i >> 8, r = i & 255, g = r >> 4, j = (r & 15) >> 1;
        ws[OFF_W2 + i] = W2[k * 128 + g + 16 * j];
    }
    if (i < 16384) {
        const int k = i >> 7, r = i & 127, g = r >> 3, j = (r & 7) >> 1;
        ws[OFF_W3 + i] = W3[k * 64 + g + 16 * j];
    }
}

template<int NA, int NB, int TYPE>
__device__ __forceinline__ void eval_body(
    int bi, const float* __restrict__ inp,
    const float* __restrict__ W1, const float* __restrict__ b1,
    const float* __restrict__ W2p, const float* __restrict__ b2,
    const float* __restrict__ W3p, const float* __restrict__ b3,
    const float* __restrict__ W4, const float* __restrict__ b4,
    float* __restrict__ ws, int N, int NB0, float* h)
{
    constexpr int JS   = NA + NB;            // 9 / 7 / 3
    constexpr int NP2  = (JS + 1) / 2;       // f32x2 pairs per jet: 5 / 4 / 2
    constexpr int NS4  = (JS + 1) / 4;       // float4 segments: 2 / 2 / 1
    constexpr int HAS2 = ((JS + 1) & 3) ? 1 : 0;  // trailing float2: 1 / 0 / 0
    constexpr int UNR2 = (NS4 == 2) ? 2 : 8; // layer-2 k-tile
    constexpr int UNR3 = (NS4 == 2) ? 4 : 8; // layer-3 k-tile

    const int t  = threadIdx.x;
    const int s  = t >> 4;                   // sample in wave (0..3)
    const int g  = t & 15;                   // lane within sample group
    const int i  = bi * 4 + s;
    const bool valid = (i < N);
    const int ii = valid ? i : (N - 1);

    const float a_in = inp[2 * ii + 1];
    float x_in;
    if constexpr (TYPE == 0)      x_in = inp[2 * ii + 0];
    else if constexpr (TYPE == 1) x_in = 0.0f;
    else                          x_in = 1.0f;

    float* hs  = h + s * SSTR;
    float* s0f = hs;                          // float4[64]
    float* s1f = hs + 256;                    // float4[64] (if NS4==2)
    float* s2f = hs + 512;                    // float2[64] (if HAS2)

    // ---------------- layers 1+2 fused, eight K-chunks of 64 ----------------
    f32x2 acc2[8][NP2];
    #pragma unroll
    for (int j = 0; j < 8; ++j)
        #pragma unroll
        for (int c = 0; c < NP2; ++c) acc2[j][c] = (f32x2){0.0f, 0.0f};

    for (int ch = 0; ch < 8; ++ch) {
        // ---- layer 1: 64 neurons/sample, 4 per lane ----
        #pragma unroll
        for (int j = 0; j < 4; ++j) {
            const int kl = g + 16 * j;
            const int nn = ch * 64 + kl;
            const float wx = W1[nn];
            const float wa = W1[512 + nn];
            float d = wx + wa;
            if (d == 0.0f) d = 1e-30f;
            const float p0 = fmaf(wx, x_in, fmaf(wa, a_in, b1[nn]));
            const float y0 = fast_tanh(p0);
            const float u0 = fmaf(-y0, y0, 1.0f);
            const float e  = wx * __builtin_amdgcn_rcpf(d);
            float y1 = 0.0f, y2 = 0.0f, y3 = 0.0f, y4 = 0.0f;
            if constexpr (NA >= 2) y1 = u0 * d;
            if constexpr (NA >= 3) { const float u1 = -2.0f * y0 * y1; y2 = 0.5f * u1 * d; }
            if constexpr (NA >= 4) { const float u2 = -fmaf(2.0f * y0, y2, y1 * y1);
                                     y3 = (1.0f/3.0f) * u2 * d; }
            if constexpr (NA >= 5) { const float u3 = -2.0f * fmaf(y0, y3, y1 * y2);
                                     y4 = 0.25f * u3 * d; }
            float4 v0;
            v0.x = y0; v0.y = e * y1; v0.z = y1;
            v0.w = (NB >= 2) ? 2.0f * e * y2 : 0.0f;
            *reinterpret_cast<float4*>(s0f + 4 * kl) = v0;
            if constexpr (NS4 == 2) {
                float4 v1;
                v1.x = y2; v1.y = 3.0f * e * y3;
                v1.z = (NA >= 4) ? y3 : 0.0f;
                v1.w = (NB >= 4) ? 4.0f * e * y4 : 0.0f;
                *reinterpret_cast<float4*>(s1f + 4 * kl) = v1;
            }
            if constexpr (HAS2) {
                float2 v2; v2.x = y4; v2.y = 0.0f;
                *reinterpret_cast<float2*>(s2f + 2 * kl) = v2;
            }
        }
        __syncthreads();

        // ---- layer 2 partial: 64 k's, 8 outputs/lane, packed FMA ----
        const float* __restrict__ Wp = W2p + ch * 16384 + 16 * g;
        #pragma unroll 1
        for (int k0 = 0; k0 < 64; k0 += UNR2) {
            #pragma unroll
            for (int kk = 0; kk < UNR2; ++kk) {
                const int k = k0 + kk;
                f32x2 jp[NP2];
                {
                    const f32x4 jv0 = *reinterpret_cast<const f32x4*>(s0f + 4 * k);
                    jp[0] = __builtin_shufflevector(jv0, jv0, 0, 1);
                    if constexpr (NP2 >= 2) jp[1] = __builtin_shufflevector(jv0, jv0, 2, 3);
                    if constexpr (NS4 == 2) {
                        const f32x4 jv1 = *reinterpret_cast<const f32x4*>(s1f + 4 * k);
                        jp[2] = __builtin_shufflevector(jv1, jv1, 0, 1);
                        if constexpr (NP2 >= 4) jp[3] = __builtin_shufflevector(jv1, jv1, 2, 3);
                    }
                    if constexpr (HAS2)
                        jp[NP2 - 1] = *reinterpret_cast<const f32x2*>(s2f + 2 * k);
                }
                f32x2 wp[8];
                {
                    const float* wb = Wp + 256 * k;
                    #pragma unroll
                    for (int q = 0; q < 4; ++q) {
                        const f32x4 wq = *reinterpret_cast<const f32x4*>(wb + 4 * q);
                        wp[2 * q]     = __builtin_shufflevector(wq, wq, 0, 1);
                        wp[2 * q + 1] = __builtin_shufflevector(wq, wq, 2, 3);
                    }
                }
                #pragma unroll
                for (int j = 0; j < 8; ++j)
                    #pragma unroll
                    for (int c = 0; c < NP2; ++c)
                        acc2[j][c] = pkfma(wp[j], jp[c], acc2[j][c]);
            }
        }
        __syncthreads();
    }

    // ------- layer-2 activation + layer 3, interleaved two-pass ------------
    // pass p (fully unrolled, rule #20): activate j=4p..4p+3 (n2=g+16j in
    // [64p,64p+64)), store h2 pairs, then layer-3 over that half's k range.
    f32x2 a32[4][NP2];
    #pragma unroll
    for (int j = 0; j < 4; ++j)
        #pragma unroll
        for (int c = 0; c < NP2; ++c) a32[j][c] = (f32x2){0.0f, 0.0f};

    #pragma unroll
    for (int pass = 0; pass < 2; ++pass) {
        __syncthreads();                     // previous buffer reads done
        #pragma unroll
        for (int jj = 0; jj < 4; ++jj) {
            const int j  = 4 * pass + jj;
            const int n2 = g + 16 * j;
            const int idx = n2 - 64 * pass;  // 0..63
            float pj[NA], qj[NB], yj[NA], rj[NB];
            #pragma unroll
            for (int c = 0; c < NA; ++c) pj[c] = acc2[j][c].x;
            pj[0] += b2[n2];
            #pragma unroll
            for (int c = 0; c < NB; ++c) qj[c] = acc2[j][c].y;
            tanh_jet<NA, NB>(pj, qj, yj, rj);
            float4 v0;
            v0.x = yj[0]; v0.y = rj[0]; v0.z = (NA >= 2) ? yj[1] : 0.0f;
            v0.w = (NB >= 2) ? rj[1] : 0.0f;
            *reinterpret_cast<float4*>(s0f + 4 * idx) = v0;
            if constexpr (NS4 == 2) {
                float4 v1;
                v1.x = yj[2]; v1.y = rj[2];
                v1.z = (NA >= 4) ? yj[3] : 0.0f;
                v1.w = (NB >= 4) ? rj[3] : 0.0f;
                *reinterpret_cast<float4*>(s1f + 4 * idx) = v1;
            }
            if constexpr (HAS2) {
                float2 v2; v2.x = yj[NA - 1]; v2.y = 0.0f;
                *reinterpret_cast<float2*>(s2f + 2 * idx) = v2;
            }
        }
        __syncthreads();

        const float* __restrict__ W3g = W3p + pass * 8192 + 8 * g;
        #pragma unroll 1
        for (int k0 = 0; k0 < 64; k0 += UNR3) {
            #pragma unroll
            for (int kk = 0; kk < UNR3; ++kk) {
                const int k = k0 + kk;
                f32x2 jp[NP2];
                {
                    const f32x4 jv0 = *reinterpret_cast<const f32x4*>(s0f + 4 * k);
                    jp[0] = __builtin_shufflevector(jv0, jv0, 0, 1);
                    if constexpr (NP2 >= 2) jp[1] = __builtin_shufflevector(jv0, jv0, 2, 3);
                    if constexpr (NS4 == 2) {
                        const f32x4 jv1 = *reinterpret_cast<const f32x4*>(s1f + 4 * k);
                        jp[2] = __builtin_shufflevector(jv1, jv1, 0, 1);
                        if constexpr (NP2 >= 4) jp[3] = __builtin_shufflevector(jv1, jv1, 2, 3);
                    }
                    if constexpr (HAS2)
                        jp[NP2 - 1] = *reinterpret_cast<const f32x2*>(s2f + 2 * k);
                }
                f32x2 wp3[4];
                {
                    const float* wb = W3g + 128 * k;
                    #pragma unroll
                    for (int q = 0; q < 2; ++q) {
                        const f32x4 wq = *reinterpret_cast<const f32x4*>(wb + 4 * q);
                        wp3[2 * q]     = __builtin_shufflevector(wq, wq, 0, 1);
                        wp3[2 * q + 1] = __builtin_shufflevector(wq, wq, 2, 3);
                    }
                }
                #pragma unroll
                for (int j = 0; j < 4; ++j)
                    #pragma unroll
                    for (int c = 0; c < NP2; ++c)
                        a32[j][c] = pkfma(wp3[j], jp[c], a32[j][c]);
            }
        }
    }

    // ---------------- layer 4 + loss (4 n3/lane, n3 = g + 16j) -------------
    float part[JS];
    #pragma unroll
    for (int c = 0; c < JS; ++c) part[c] = 0.0f;
    #pragma unroll
    for (int j = 0; j < 4; ++j) {
        const int n3 = g + 16 * j;
        float pj[NA], qj[NB], yj[NA], rj[NB];
        #pragma unroll
        for (int c = 0; c < NA; ++c) pj[c] = a32[j][c].x;
        pj[0] += b3[n3];
        #pragma unroll
        for (int c = 0; c < NB; ++c) qj[c] = a32[j][c].y;
        tanh_jet<NA, NB>(pj, qj, yj, rj);
        const float w4 = W4[n3];
        #pragma unroll
        for (int c = 0; c < NA; ++c) part[c] = fmaf(w4, yj[c], part[c]);
        #pragma unroll
        for (int c = 0; c < NB; ++c) part[NA + c] = fmaf(w4, rj[c], part[NA + c]);
    }
    #pragma unroll
    for (int m = 1; m <= 8; m <<= 1)
        #pragma unroll
        for (int c = 0; c < JS; ++c)
            part[c] += __shfl_xor(part[c], m, 64);
    // all 16 lanes of each group now hold their sample's output jet

    const float A0 = part[0] + b4[0];
    float t0 = 0.0f, t1 = 0.0f, t2 = 0.0f;
    constexpr float CC = 1.0f;   // P/(E*I)
    if constexpr (TYPE == 0) {
        const float gx = 6.0f * part[NA + 3];
        const float ga = 24.0f * part[4] - gx;
        t0 = (gx + CC) * (gx + CC) + (ga + CC) * (ga + CC);
    }
    if constexpr (TYPE == 1) {
        t0 = A0 * A0;
        const float gx = part[NA + 0];
        const float ga = part[1] - gx;
        t1 = gx * gx + ga * ga;
    }
    if constexpr (TYPE == 2) {
        const float wa = a_in * A0;
        t0 = wa * wa;
        const float g2x = part[NA + 1];
        const float g2a = 2.0f * part[2] - g2x;
        t1 = g2x * g2x + g2a * g2a;
        const float g3x = 2.0f * part[NA + 2];
        const float g3a = 6.0f * part[3] - g3x;
        const float om = 1.0f - a_in;
        t2 = om * om * (g3x * g3x + g3a * g3a);
    }
    if (!valid) { t0 = 0.0f; t1 = 0.0f; t2 = 0.0f; }

    // sum the wave's 4 samples (cross-group butterflies)
    t0 += __shfl_xor(t0, 16, 64); t0 += __shfl_xor(t0, 32, 64);
    if constexpr (TYPE != 0) { t1 += __shfl_xor(t1, 16, 64); t1 += __shfl_xor(t1, 32, 64); }
    if constexpr (TYPE == 2) { t2 += __shfl_xor(t2, 16, 64); t2 += __shfl_xor(t2, 32, 64); }

    if (t == 0) {
        if constexpr (TYPE == 0) {
            ws[bi] = t0;
        } else if constexpr (TYPE == 1) {
            ws[NB0 + bi]     = t0;
            ws[2 * NB0 + bi] = t1;
        } else {
            ws[3 * NB0 + bi] = t0;
            ws[4 * NB0 + bi] = t1;
            ws[5 * NB0 + bi] = t2;
        }
    }
}

__global__ __launch_bounds__(64, 2)
void pinn_fat(const float* __restrict__ inp,
              const float* __restrict__ W1, const float* __restrict__ b1,
              const float* __restrict__ W2p, const float* __restrict__ b2,
              const float* __restrict__ W3p, const float* __restrict__ b3,
              const float* __restrict__ W4, const float* __restrict__ b4,
              float* __restrict__ ws, int N, int NB0)
{
    __shared__ __align__(16) float h[4 * SSTR];    // 10368 B
    const int b = blockIdx.x;
    if (b < NB0)
        eval_body<5, 4, 0>(b, inp, W1, b1, W2p, b2, W3p, b3, W4, b4, ws, N, NB0, h);
    else if (b < 2 * NB0)
        eval_body<4, 3, 2>(b - NB0, inp, W1, b1, W2p, b2, W3p, b3, W4, b4, ws, N, NB0, h);
    else
        eval_body<2, 1, 1>(b - 2 * NB0, inp, W1, b1, W2p, b2, W3p, b3, W4, b4, ws, N, NB0, h);
}

__global__ __launch_bounds__(1024)
void pinn_reduce(const float* __restrict__ ws, float* __restrict__ out,
                 int G, float invN, float inv2N)
{
    __shared__ float sh[16 * 6];
    float s[6];
    #pragma unroll
    for (int q = 0; q < 6; ++q) {
        float acc = 0.0f;
        for (int i = threadIdx.x; i < G; i += 1024) acc += ws[q * G + i];
        #pragma unroll
        for (int m = 1; m <= 32; m <<= 1) acc += __shfl_xor(acc, m, 64);
        s[q] = acc;
    }
    const int wid = threadIdx.x >> 6;
    if ((threadIdx.x & 63) == 0) {
        #pragma unroll
        for (int q = 0; q < 6; ++q) sh[wid * 6 + q] = s[q];
    }
    __syncthreads();
    if (threadIdx.x == 0) {
        float r[6];
        #pragma unroll
        for (int q = 0; q < 6; ++q) {
            float acc = 0.0f;
            for (int w = 0; w < 16; ++w) acc += sh[w * 6 + q];
            r[q] = acc;
        }
        const float pde   = r[0] * inv2N;
        const float w0    = r[1] * invN;
        const float w0x   = r[2] * inv2N;
        const float wL    = r[3] * invN;
        const float wLxx  = r[4] * inv2N;
        const float wLxxx = r[5] * inv2N;
        out[0] = pde + w0 + w0x + wL + wLxx + wLxxx;
        out[1] = pde;
        out[2] = w0;
        out[3] = w0x;
        out[4] = wL;
        out[5] = wLxx;
        out[6] = wLxxx;
    }
}

extern "C" void kernel_launch(void* const* d_in, const int* in_sizes, int n_in,
                              void* d_out, int out_size, void* d_ws, size_t ws_size,
                              hipStream_t stream) {
    const float* inp = (const float*)d_in[0];
    const float* W1  = (const float*)d_in[1];
    const float* b1  = (const float*)d_in[2];
    const float* W2  = (const float*)d_in[3];
    const float* b2  = (const float*)d_in[4];
    const float* W3  = (const float*)d_in[5];
    const float* b3  = (const float*)d_in[6];
    const float* W4  = (const float*)d_in[7];
    const float* b4  = (const float*)d_in[8];
    float* ws  = (float*)d_ws;
    float* out = (float*)d_out;

    const int N   = in_sizes[0] / 2;   // 32768
    const int NB0 = (N + 3) / 4;       // blocks per eval type (4 samples/block)

    // permute + duplicate W2/W3 for packed-FMA lane ownership (into d_ws)
    pinn_prep<<<dim3(512), dim3(256), 0, stream>>>(W2, W3, ws);

    pinn_fat<<<dim3(3 * NB0), dim3(64), 0, stream>>>(
        inp, W1, b1, ws + OFF_W2, b2, ws + OFF_W3, b3, W4, b4, ws, N, NB0);
    pinn_reduce<<<dim3(1), dim3(1024), 0, stream>>>(
        ws, out, NB0, 1.0f / (float)N, 0.5f / (float)N);
}

// Round 11
// 1236.099 us; speedup vs baseline: 2.3220x; 2.3220x over previous
//
#include <hip/hip_runtime.h>
#include <math.h>

// ---------------------------------------------------------------------------
// PINN beam loss via forward-mode bivariate jets (v11 = v9 + 2-wave blocks).
// Jet of f(z + t*(1,1) + s*(1,0)):  y[k]=coeff t^k, z[k]=coeff t^k s.
// Layer-1: pre-act = p0 + d*t + wx*s  =>  z[k] = (k+1)*(wx/d)*y[k+1] exactly.
//
// v9 analysis: single-wave (64-thread) blocks cap at ~8 workgroups/CU
// (occupancy 23%) regardless of LDS/VGPR headroom. Fix: 128-thread blocks
// (2 waves, 8 samples/block, 16 lanes/sample) -> 7 blocks x 2 waves =
// ~14 waves/CU (~44%) within the same LDS budget. Inner loops identical to
// v9 (scalar fmaf; v10's packed-FMA experiment regressed 2.4x: scalarized
// shuffles + doubled weight VMEM made it stall-bound at VALUBusy 26%).
// LDS per sample (SoA float4 segments, 16B aligned):
//   seg0[k]=(y0,z0,y1,z1)  seg1[k]=(y2,z2,y3,z3)  seg2[k]=(y4,0)
// ---------------------------------------------------------------------------

#define SSTR 648            // per-sample LDS float stride (64*10 + 8 skew)
#define OFF_W2 65536        // ws float offset of W2perm [512][16][8]
#define OFF_W3 131072       // ws float offset of W3perm [128][16][4]

__device__ __forceinline__ float fast_tanh(float x) {
    float ax = fabsf(x);
    float e  = __expf(-2.0f * ax);
    float y  = (1.0f - e) * __builtin_amdgcn_rcpf(1.0f + e);
    return copysignf(y, x);
}

template<int NA, int NB>
__device__ __forceinline__ void tanh_jet(const float (&p)[NA], const float (&q)[NB],
                                         float (&y)[NA], float (&r)[NB]) {
    constexpr int NU = ((NA - 1) > NB ? (NA - 1) : NB);
    float u[NU];
    y[0] = fast_tanh(p[0]);
    u[0] = fmaf(-y[0], y[0], 1.0f);
    if constexpr (NA >= 2) y[1] = u[0] * p[1];
    if constexpr (NU >= 2) u[1] = -2.0f * y[0] * y[1];
    if constexpr (NA >= 3) y[2] = fmaf(u[0], p[2], 0.5f * u[1] * p[1]);
    if constexpr (NU >= 3) u[2] = -fmaf(2.0f * y[0], y[2], y[1] * y[1]);
    if constexpr (NA >= 4) y[3] = fmaf(u[0], p[3], fmaf((2.0f/3.0f) * u[1], p[2],
                                       (1.0f/3.0f) * u[2] * p[1]));
    if constexpr (NU >= 4) u[3] = -2.0f * fmaf(y[0], y[3], y[1] * y[2]);
    if constexpr (NA >= 5) y[4] = fmaf(u[0], p[4], fmaf(0.75f * u[1], p[3],
                                       fmaf(0.5f * u[2], p[2], 0.25f * u[3] * p[1])));
    #pragma unroll
    for (int k = 0; k < NB; ++k) {
        float s = 0.0f;
        #pragma unroll
        for (int j = 0; j <= k; ++j) s = fmaf(u[j], q[k - j], s);
        r[k] = s;
    }
}

// Permute weights for stride-16 per-lane output ownership:
//   W2perm[k*128 + g*8 + j] = W2[k*128 + g + 16*j]   (k<512, g<16, j<8)
//   W3perm[k*64  + g*4 + j] = W3[k*64  + g + 16*j]   (k<128, g<16, j<4)
__global__ __launch_bounds__(256)
void pinn_prep(const float* __restrict__ W2, const float* __restrict__ W3,
               float* __restrict__ ws)
{
    const int i = blockIdx.x * 256 + threadIdx.x;
    if (i < 65536) {
        const int k = i >> 7, r = i & 127, g = r >> 3, j = r & 7;
        ws[OFF_W2 + i] = W2[k * 128 + g + 16 * j];
    }
    if (i < 8192) {
        const int k = i >> 6, r = i & 63, g = r >> 2, j = r & 3;
        ws[OFF_W3 + i] = W3[k * 64 + g + 16 * j];
    }
}

template<int NA, int NB, int TYPE>
__device__ __forceinline__ void eval_body(
    int bi, const float* __restrict__ inp,
    const float* __restrict__ W1, const float* __restrict__ b1,
    const float* __restrict__ W2perm, const float* __restrict__ b2,
    const float* __restrict__ W3perm, const float* __restrict__ b3,
    const float* __restrict__ W4, const float* __restrict__ b4,
    float* __restrict__ ws, int N, int NB0, float* h, float (*red)[3])
{
    constexpr int JS   = NA + NB;            // 9 / 7 / 3
    constexpr int NS4  = (JS + 1) / 4;       // float4 segments: 2 / 2 / 1
    constexpr int HAS2 = ((JS + 1) & 3) ? 1 : 0;  // trailing float2: 1 / 0 / 0
    constexpr int UNR2 = (NS4 == 2) ? 2 : 8; // layer-2 k-tile (small live set)
    constexpr int UNR3 = (NS4 == 2) ? 4 : 8; // layer-3 k-tile

    const int t  = threadIdx.x;              // 0..127
    const int wv = t >> 6;                   // wave in block (0..1)
    const int s  = t >> 4;                   // sample in block (0..7)
    const int g  = t & 15;                   // lane within sample group
    const int i  = bi * 8 + s;
    const bool valid = (i < N);
    const int ii = valid ? i : (N - 1);

    const float a_in = inp[2 * ii + 1];
    float x_in;
    if constexpr (TYPE == 0)      x_in = inp[2 * ii + 0];
    else if constexpr (TYPE == 1) x_in = 0.0f;
    else                          x_in = 1.0f;

    float* hs  = h + s * SSTR;
    float* s0f = hs;                          // float4[64]
    float* s1f = hs + 256;                    // float4[64] (if NS4==2)
    float* s2f = hs + 512;                    // float2[64] (if HAS2)

    // ---------------- layers 1+2 fused, eight K-chunks of 64 ----------------
    float acc_a[8][NA];
    float acc_b[8][NB];
    #pragma unroll
    for (int j = 0; j < 8; ++j) {
        #pragma unroll
        for (int c = 0; c < NA; ++c) acc_a[j][c] = 0.0f;
        #pragma unroll
        for (int c = 0; c < NB; ++c) acc_b[j][c] = 0.0f;
    }

    for (int ch = 0; ch < 8; ++ch) {
        // ---- layer 1: 64 neurons/sample, 4 per lane ----
        #pragma unroll
        for (int j = 0; j < 4; ++j) {
            const int kl = g + 16 * j;
            const int nn = ch * 64 + kl;
            const float wx = W1[nn];
            const float wa = W1[512 + nn];
            float d = wx + wa;
            if (d == 0.0f) d = 1e-30f;
            const float p0 = fmaf(wx, x_in, fmaf(wa, a_in, b1[nn]));
            const float y0 = fast_tanh(p0);
            const float u0 = fmaf(-y0, y0, 1.0f);
            const float e  = wx * __builtin_amdgcn_rcpf(d);
            float y1 = 0.0f, y2 = 0.0f, y3 = 0.0f, y4 = 0.0f;
            if constexpr (NA >= 2) y1 = u0 * d;
            if constexpr (NA >= 3) { const float u1 = -2.0f * y0 * y1; y2 = 0.5f * u1 * d; }
            if constexpr (NA >= 4) { const float u2 = -fmaf(2.0f * y0, y2, y1 * y1);
                                     y3 = (1.0f/3.0f) * u2 * d; }
            if constexpr (NA >= 5) { const float u3 = -2.0f * fmaf(y0, y3, y1 * y2);
                                     y4 = 0.25f * u3 * d; }
            float4 v0;
            v0.x = y0; v0.y = e * y1; v0.z = y1;
            v0.w = (NB >= 2) ? 2.0f * e * y2 : 0.0f;
            *reinterpret_cast<float4*>(s0f + 4 * kl) = v0;
            if constexpr (NS4 == 2) {
                float4 v1;
                v1.x = y2; v1.y = 3.0f * e * y3;
                v1.z = (NA >= 4) ? y3 : 0.0f;
                v1.w = (NB >= 4) ? 4.0f * e * y4 : 0.0f;
                *reinterpret_cast<float4*>(s1f + 4 * kl) = v1;
            }
            if constexpr (HAS2) {
                float2 v2; v2.x = y4; v2.y = 0.0f;
                *reinterpret_cast<float2*>(s2f + 2 * kl) = v2;
            }
        }
        __syncthreads();

        // ---- layer 2 partial: 64 k's, 8 outputs/lane (n2 = g + 16j) ----
        const float* __restrict__ Wp = W2perm + ch * 8192 + 8 * g;
        #pragma unroll 1
        for (int k0 = 0; k0 < 64; k0 += UNR2) {
            #pragma unroll
            for (int kk = 0; kk < UNR2; ++kk) {
                const int k = k0 + kk;
                const float4 jv0 = *reinterpret_cast<const float4*>(s0f + 4 * k);
                float4 jv1; float2 jv2;
                if constexpr (NS4 == 2) jv1 = *reinterpret_cast<const float4*>(s1f + 4 * k);
                if constexpr (HAS2)     jv2 = *reinterpret_cast<const float2*>(s2f + 2 * k);
                const float4 wva = *reinterpret_cast<const float4*>(Wp + 128 * k);
                const float4 wvb = *reinterpret_cast<const float4*>(Wp + 128 * k + 4);

                float ya[NA], za[NB];
                ya[0] = jv0.x; za[0] = jv0.y; ya[1] = jv0.z;
                if constexpr (NB >= 2) za[1] = jv0.w;
                if constexpr (NS4 == 2) {
                    ya[2] = jv1.x; za[2] = jv1.y;
                    if constexpr (NA >= 4) ya[3] = jv1.z;
                    if constexpr (NB >= 4) za[3] = jv1.w;
                }
                if constexpr (HAS2) ya[4] = jv2.x;
                const float w[8] = {wva.x, wva.y, wva.z, wva.w,
                                    wvb.x, wvb.y, wvb.z, wvb.w};
                #pragma unroll
                for (int j = 0; j < 8; ++j) {
                    #pragma unroll
                    for (int c = 0; c < NA; ++c)
                        acc_a[j][c] = fmaf(w[j], ya[c], acc_a[j][c]);
                    #pragma unroll
                    for (int c = 0; c < NB; ++c)
                        acc_b[j][c] = fmaf(w[j], za[c], acc_b[j][c]);
                }
            }
        }
        __syncthreads();
    }

    // ------- layer-2 activation + layer 3, interleaved two-pass ------------
    // pass p (FULLY UNROLLED, rule #20): activate j=4p..4p+3 (n2 = g+16j in
    // [64p,64p+64)), store those h2 entries, then layer-3 over that half.
    float a3[4][NA], b3c[4][NB];
    #pragma unroll
    for (int j = 0; j < 4; ++j) {
        #pragma unroll
        for (int c = 0; c < NA; ++c) a3[j][c] = 0.0f;
        #pragma unroll
        for (int c = 0; c < NB; ++c) b3c[j][c] = 0.0f;
    }
    #pragma unroll
    for (int pass = 0; pass < 2; ++pass) {
        __syncthreads();                     // previous buffer reads done
        #pragma unroll
        for (int jj = 0; jj < 4; ++jj) {
            const int j  = 4 * pass + jj;
            const int n2 = g + 16 * j;
            const int idx = n2 - 64 * pass;  // 0..63
            float pj[NA], qj[NB], yj[NA], rj[NB];
            #pragma unroll
            for (int c = 0; c < NA; ++c) pj[c] = acc_a[j][c];
            pj[0] += b2[n2];
            #pragma unroll
            for (int c = 0; c < NB; ++c) qj[c] = acc_b[j][c];
            tanh_jet<NA, NB>(pj, qj, yj, rj);
            float4 v0;
            v0.x = yj[0]; v0.y = rj[0]; v0.z = (NA >= 2) ? yj[1] : 0.0f;
            v0.w = (NB >= 2) ? rj[1] : 0.0f;
            *reinterpret_cast<float4*>(s0f + 4 * idx) = v0;
            if constexpr (NS4 == 2) {
                float4 v1;
                v1.x = yj[2]; v1.y = rj[2];
                v1.z = (NA >= 4) ? yj[3] : 0.0f;
                v1.w = (NB >= 4) ? rj[3] : 0.0f;
                *reinterpret_cast<float4*>(s1f + 4 * idx) = v1;
            }
            if constexpr (HAS2) {
                float2 v2; v2.x = yj[NA - 1]; v2.y = 0.0f;
                *reinterpret_cast<float2*>(s2f + 2 * idx) = v2;
            }
        }
        __syncthreads();

        const float* __restrict__ W3g = W3perm + pass * 4096 + 4 * g;
        #pragma unroll 1
        for (int k0 = 0; k0 < 64; k0 += UNR3) {
            #pragma unroll
            for (int kk = 0; kk < UNR3; ++kk) {
                const int k = k0 + kk;
                const float4 jv0 = *reinterpret_cast<const float4*>(s0f + 4 * k);
                float4 jv1; float2 jv2;
                if constexpr (NS4 == 2) jv1 = *reinterpret_cast<const float4*>(s1f + 4 * k);
                if constexpr (HAS2)     jv2 = *reinterpret_cast<const float2*>(s2f + 2 * k);
                const float4 wv4 = *reinterpret_cast<const float4*>(W3g + 64 * k);

                float ya[NA], za[NB];
                ya[0] = jv0.x; za[0] = jv0.y; ya[1] = jv0.z;
                if constexpr (NB >= 2) za[1] = jv0.w;
                if constexpr (NS4 == 2) {
                    ya[2] = jv1.x; za[2] = jv1.y;
                    if constexpr (NA >= 4) ya[3] = jv1.z;
                    if constexpr (NB >= 4) za[3] = jv1.w;
                }
                if constexpr (HAS2) ya[4] = jv2.x;
                const float w[4] = {wv4.x, wv4.y, wv4.z, wv4.w};
                #pragma unroll
                for (int j = 0; j < 4; ++j) {
                    #pragma unroll
                    for (int c = 0; c < NA; ++c)
                        a3[j][c] = fmaf(w[j], ya[c], a3[j][c]);
                    #pragma unroll
                    for (int c = 0; c < NB; ++c)
                        b3c[j][c] = fmaf(w[j], za[c], b3c[j][c]);
                }
            }
        }
    }

    // ---------------- layer 4 + loss (4 n3/lane, n3 = g + 16j) -------------
    float part[JS];
    #pragma unroll
    for (int c = 0; c < JS; ++c) part[c] = 0.0f;
    #pragma unroll
    for (int j = 0; j < 4; ++j) {
        const int n3 = g + 16 * j;
        float pj[NA], qj[NB], yj[NA], rj[NB];
        #pragma unroll
        for (int c = 0; c < NA; ++c) pj[c] = a3[j][c];
        pj[0] += b3[n3];
        #pragma unroll
        for (int c = 0; c < NB; ++c) qj[c] = b3c[j][c];
        tanh_jet<NA, NB>(pj, qj, yj, rj);
        const float w4 = W4[n3];
        #pragma unroll
        for (int c = 0; c < NA; ++c) part[c] = fmaf(w4, yj[c], part[c]);
        #pragma unroll
        for (int c = 0; c < NB; ++c) part[NA + c] = fmaf(w4, rj[c], part[NA + c]);
    }
    #pragma unroll
    for (int m = 1; m <= 8; m <<= 1)
        #pragma unroll
        for (int c = 0; c < JS; ++c)
            part[c] += __shfl_xor(part[c], m, 64);
    // all 16 lanes of each group now hold their sample's output jet

    const float A0 = part[0] + b4[0];
    float t0 = 0.0f, t1 = 0.0f, t2 = 0.0f;
    constexpr float CC = 1.0f;   // P/(E*I)
    if constexpr (TYPE == 0) {
        const float gx = 6.0f * part[NA + 3];
        const float ga = 24.0f * part[4] - gx;
        t0 = (gx + CC) * (gx + CC) + (ga + CC) * (ga + CC);
    }
    if constexpr (TYPE == 1) {
        t0 = A0 * A0;
        const float gx = part[NA + 0];
        const float ga = part[1] - gx;
        t1 = gx * gx + ga * ga;
    }
    if constexpr (TYPE == 2) {
        const float wa = a_in * A0;
        t0 = wa * wa;
        const float g2x = part[NA + 1];
        const float g2a = 2.0f * part[2] - g2x;
        t1 = g2x * g2x + g2a * g2a;
        const float g3x = 2.0f * part[NA + 2];
        const float g3a = 6.0f * part[3] - g3x;
        const float om = 1.0f - a_in;
        t2 = om * om * (g3x * g3x + g3a * g3a);
    }
    if (!valid) { t0 = 0.0f; t1 = 0.0f; t2 = 0.0f; }

    // sum the wave's 4 samples, then the block's 2 waves via LDS
    t0 += __shfl_xor(t0, 16, 64); t0 += __shfl_xor(t0, 32, 64);
    if constexpr (TYPE != 0) { t1 += __shfl_xor(t1, 16, 64); t1 += __shfl_xor(t1, 32, 64); }
    if constexpr (TYPE == 2) { t2 += __shfl_xor(t2, 16, 64); t2 += __shfl_xor(t2, 32, 64); }

    if ((t & 63) == 0) { red[wv][0] = t0; red[wv][1] = t1; red[wv][2] = t2; }
    __syncthreads();
    if (t == 0) {
        t0 = red[0][0] + red[1][0];
        t1 = red[0][1] + red[1][1];
        t2 = red[0][2] + red[1][2];
        if constexpr (TYPE == 0) {
            ws[bi] = t0;
        } else if constexpr (TYPE == 1) {
            ws[NB0 + bi]     = t0;
            ws[2 * NB0 + bi] = t1;
        } else {
            ws[3 * NB0 + bi] = t0;
            ws[4 * NB0 + bi] = t1;
            ws[5 * NB0 + bi] = t2;
        }
    }
}

__global__ __launch_bounds__(128, 2)
void pinn_fat(const float* __restrict__ inp,
              const float* __restrict__ W1, const float* __restrict__ b1,
              const float* __restrict__ W2perm, const float* __restrict__ b2,
              const float* __restrict__ W3perm, const float* __restrict__ b3,
              const float* __restrict__ W4, const float* __restrict__ b4,
              float* __restrict__ ws, int N, int NB0)
{
    __shared__ __align__(16) float h[8 * SSTR];    // 20736 B -> 7 blocks/CU
    __shared__ float red[2][3];
    const int b = blockIdx.x;
    if (b < NB0)
        eval_body<5, 4, 0>(b, inp, W1, b1, W2perm, b2, W3perm, b3, W4, b4, ws, N, NB0, h, red);
    else if (b < 2 * NB0)
        eval_body<4, 3, 2>(b - NB0, inp, W1, b1, W2perm, b2, W3perm, b3, W4, b4, ws, N, NB0, h, red);
    else
        eval_body<2, 1, 1>(b - 2 * NB0, inp, W1, b1, W2perm, b2, W3perm, b3, W4, b4, ws, N, NB0, h, red);
}

__global__ __launch_bounds__(1024)
void pinn_reduce(const float* __restrict__ ws, float* __restrict__ out,
                 int G, float invN, float inv2N)
{
    __shared__ float sh[16 * 6];
    float s[6];
    #pragma unroll
    for (int q = 0; q < 6; ++q) {
        float acc = 0.0f;
        for (int i = threadIdx.x; i < G; i += 1024) acc += ws[q * G + i];
        #pragma unroll
        for (int m = 1; m <= 32; m <<= 1) acc += __shfl_xor(acc, m, 64);
        s[q] = acc;
    }
    const int wid = threadIdx.x >> 6;
    if ((threadIdx.x & 63) == 0) {
        #pragma unroll
        for (int q = 0; q < 6; ++q) sh[wid * 6 + q] = s[q];
    }
    __syncthreads();
    if (threadIdx.x == 0) {
        float r[6];
        #pragma unroll
        for (int q = 0; q < 6; ++q) {
            float acc = 0.0f;
            for (int w = 0; w < 16; ++w) acc += sh[w * 6 + q];
            r[q] = acc;
        }
        const float pde   = r[0] * inv2N;
        const float w0    = r[1] * invN;
        const float w0x   = r[2] * inv2N;
        const float wL    = r[3] * invN;
        const float wLxx  = r[4] * inv2N;
        const float wLxxx = r[5] * inv2N;
        out[0] = pde + w0 + w0x + wL + wLxx + wLxxx;
        out[1] = pde;
        out[2] = w0;
        out[3] = w0x;
        out[4] = wL;
        out[5] = wLxx;
        out[6] = wLxxx;
    }
}

extern "C" void kernel_launch(void* const* d_in, const int* in_sizes, int n_in,
                              void* d_out, int out_size, void* d_ws, size_t ws_size,
                              hipStream_t stream) {
    const float* inp = (const float*)d_in[0];
    const float* W1  = (const float*)d_in[1];
    const float* b1  = (const float*)d_in[2];
    const float* W2  = (const float*)d_in[3];
    const float* b2  = (const float*)d_in[4];
    const float* W3  = (const float*)d_in[5];
    const float* b3  = (const float*)d_in[6];
    const float* W4  = (const float*)d_in[7];
    const float* b4  = (const float*)d_in[8];
    float* ws  = (float*)d_ws;
    float* out = (float*)d_out;

    const int N   = in_sizes[0] / 2;   // 32768
    const int NB0 = (N + 7) / 8;       // blocks per eval type (8 samples/block)

    // permute W2/W3 for stride-16 lane->output ownership (into d_ws)
    pinn_prep<<<dim3(256), dim3(256), 0, stream>>>(W2, W3, ws);

    pinn_fat<<<dim3(3 * NB0), dim3(128), 0, stream>>>(
        inp, W1, b1, ws + OFF_W2, b2, ws + OFF_W3, b3, W4, b4, ws, N, NB0);
    pinn_reduce<<<dim3(1), dim3(1024), 0, stream>>>(
        ws, out, NB0, 1.0f / (float)N, 0.5f / (float)N);
}

// Round 12
// 844.193 us; speedup vs baseline: 3.4000x; 1.4642x over previous
//
#include <hip/hip_runtime.h>
#include <math.h>

// ---------------------------------------------------------------------------
// PINN beam loss via forward-mode bivariate jets (v12 = v9 + fp16 dot2 layer2).
// Jet of f(z + t*(1,1) + s*(1,0)):  y[k]=coeff t^k, z[k]=coeff t^k s.
// Layer-1: pre-act = p0 + d*t + wx*s  =>  z[k] = (k+1)*(wx/d)*y[k+1] exactly.
//
// Layer 2 (75% of cycles) uses v_dot2_f32_f16: jets stored as half2 pairs
// over k (pair = the two neurons one lane already owns: k and k+16), weights
// pre-paired+fp16 in prep. 72 dot2 per 2 k's vs 144 scalar FMA; LDS and
// weight VMEM bytes halve. fp32 accumulators + fp32 tanh chain unchanged.
// All jet values are O(1) (e*y_{k+1} cancels 1/d algebraically) -> fp16 safe;
// expected absmax ~1e-3 vs threshold 2.1e-2.
// Mapping (v9, best known): 64-thread blocks, 4 samples/wave, 16 lanes/sample,
// stride-16 output ownership, fully-unrolled pass loop (rule #20).
// ---------------------------------------------------------------------------

#define SSTR 648           // per-sample LDS float stride (16B-multiple)
#define OFF_W2U 65536      // uint offset in ws of W2pair [8][32][16][8] (32768)
#define OFF_W3F 98304      // float offset in ws of W3perm [128][16][4] (8192)

typedef _Float16 half2_t __attribute__((ext_vector_type(2)));

__device__ __forceinline__ float dot2acc(half2_t a, half2_t b, float c) {
#if __has_builtin(__builtin_amdgcn_fdot2)
    return __builtin_amdgcn_fdot2(a, b, c, false);
#else
    return fmaf((float)a.y, (float)b.y, fmaf((float)a.x, (float)b.x, c));
#endif
}

__device__ __forceinline__ unsigned int pkrtz(float lo, float hi) {
    return __builtin_bit_cast(unsigned int, __builtin_amdgcn_cvt_pkrtz(lo, hi));
}

__device__ __forceinline__ float fast_tanh(float x) {
    float ax = fabsf(x);
    float e  = __expf(-2.0f * ax);
    float y  = (1.0f - e) * __builtin_amdgcn_rcpf(1.0f + e);
    return copysignf(y, x);
}

template<int NA, int NB>
__device__ __forceinline__ void tanh_jet(const float (&p)[NA], const float (&q)[NB],
                                         float (&y)[NA], float (&r)[NB]) {
    constexpr int NU = ((NA - 1) > NB ? (NA - 1) : NB);
    float u[NU];
    y[0] = fast_tanh(p[0]);
    u[0] = fmaf(-y[0], y[0], 1.0f);
    if constexpr (NA >= 2) y[1] = u[0] * p[1];
    if constexpr (NU >= 2) u[1] = -2.0f * y[0] * y[1];
    if constexpr (NA >= 3) y[2] = fmaf(u[0], p[2], 0.5f * u[1] * p[1]);
    if constexpr (NU >= 3) u[2] = -fmaf(2.0f * y[0], y[2], y[1] * y[1]);
    if constexpr (NA >= 4) y[3] = fmaf(u[0], p[3], fmaf((2.0f/3.0f) * u[1], p[2],
                                       (1.0f/3.0f) * u[2] * p[1]));
    if constexpr (NU >= 4) u[3] = -2.0f * fmaf(y[0], y[3], y[1] * y[2]);
    if constexpr (NA >= 5) y[4] = fmaf(u[0], p[4], fmaf(0.75f * u[1], p[3],
                                       fmaf(0.5f * u[2], p[2], 0.25f * u[3] * p[1])));
    #pragma unroll
    for (int k = 0; k < NB; ++k) {
        float s = 0.0f;
        #pragma unroll
        for (int j = 0; j <= k; ++j) s = fmaf(u[j], q[k - j], s);
        r[k] = s;
    }
}

// layer-1 jet of neuron nn, interleaved [y0,z0,y1,z1,...,y_{NB-1},z_{NB-1},y_{NA-1}]
template<int NA, int NB, int NC>
__device__ __forceinline__ void l1jet(int nn, float x_in, float a_in,
                                      const float* __restrict__ W1,
                                      const float* __restrict__ b1,
                                      float (&jt)[NC]) {
    const float wx = W1[nn];
    const float wa = W1[512 + nn];
    float d = wx + wa;
    if (d == 0.0f) d = 1e-30f;
    const float p0 = fmaf(wx, x_in, fmaf(wa, a_in, b1[nn]));
    const float y0 = fast_tanh(p0);
    const float u0 = fmaf(-y0, y0, 1.0f);
    const float e  = wx * __builtin_amdgcn_rcpf(d);
    float y1 = 0.0f, y2 = 0.0f, y3 = 0.0f, y4 = 0.0f;
    if constexpr (NA >= 2) y1 = u0 * d;
    if constexpr (NA >= 3) { const float u1 = -2.0f * y0 * y1; y2 = 0.5f * u1 * d; }
    if constexpr (NA >= 4) { const float u2 = -fmaf(2.0f * y0, y2, y1 * y1);
                             y3 = (1.0f/3.0f) * u2 * d; }
    if constexpr (NA >= 5) { const float u3 = -2.0f * fmaf(y0, y3, y1 * y2);
                             y4 = 0.25f * u3 * d; }
    jt[0] = y0;
    jt[1] = e * y1;
    if constexpr (NB >= 2) { jt[2] = y1; jt[3] = 2.0f * e * y2; }
    if constexpr (NB >= 3) { jt[4] = y2; jt[5] = 3.0f * e * y3; }
    if constexpr (NB >= 4) { jt[6] = y3; jt[7] = 4.0f * e * y4; }
    if constexpr (NA == 2) jt[2 * NB] = y1;
    else if constexpr (NA == 3) jt[2 * NB] = y2;
    else if constexpr (NA == 4) jt[2 * NB] = y3;
    else                        jt[2 * NB] = y4;
}

// Pre-pair + fp16-convert W2 (slot pairing: s<16 -> (s,s+16); s>=16 -> (s+16,s+32)
// within each 64-chunk), and permute W3 for stride-16 lane ownership (fp32).
__global__ __launch_bounds__(256)
void pinn_prep(const float* __restrict__ W2, const float* __restrict__ W3,
               float* __restrict__ ws)
{
    const int i = blockIdx.x * 256 + threadIdx.x;
    if (i < 32768) {
        const int ch = i >> 12, rem = i & 4095, s = rem >> 7,
                  rem2 = rem & 127, g = rem2 >> 3, j = rem2 & 7;
        const int kAl = (s < 16) ? s : s + 16;
        const int kA = ch * 64 + kAl;
        const int kB = kA + 16;
        const int n  = g + 16 * j;
        half2_t hv;
        hv.x = (_Float16)W2[kA * 128 + n];    // RNE
        hv.y = (_Float16)W2[kB * 128 + n];
        reinterpret_cast<unsigned int*>(ws)[OFF_W2U + i] = __builtin_bit_cast(unsigned int, hv);
    }
    if (i < 8192) {
        const int k = i >> 6, r = i & 63, g = r >> 2, j = r & 3;
        ws[OFF_W3F + i] = W3[k * 64 + g + 16 * j];
    }
}

template<int NA, int NB, int TYPE>
__device__ __forceinline__ void eval_body(
    int bi, const float* __restrict__ inp,
    const float* __restrict__ W1, const float* __restrict__ b1,
    const unsigned int* __restrict__ W2p, const float* __restrict__ b2,
    const float* __restrict__ W3perm, const float* __restrict__ b3,
    const float* __restrict__ W4, const float* __restrict__ b4,
    float* __restrict__ ws, int N, int NB0, float* h)
{
    constexpr int JS   = NA + NB;            // 9 / 7 / 3 components
    constexpr int NC   = JS;
    constexpr int ST   = (NC + 3) & ~3;      // slot stride dwords: 12 / 8 / 4
    constexpr int NS4  = (JS + 1) / 4;       // fp32 seg count (h2 phase): 2/2/1
    constexpr int HAS2 = ((JS + 1) & 3) ? 1 : 0;
    constexpr int UNRS = (NC > 4) ? 2 : 8;   // layer-2 slot tile
    constexpr int UNR3 = (NS4 == 2) ? 4 : 8; // layer-3 k tile

    const int t  = threadIdx.x;
    const int s  = t >> 4;                   // sample in wave (0..3)
    const int g  = t & 15;                   // lane within sample group
    const int i  = bi * 4 + s;
    const bool valid = (i < N);
    const int ii = valid ? i : (N - 1);

    const float a_in = inp[2 * ii + 1];
    float x_in;
    if constexpr (TYPE == 0)      x_in = inp[2 * ii + 0];
    else if constexpr (TYPE == 1) x_in = 0.0f;
    else                          x_in = 1.0f;

    float* hs = h + s * SSTR;
    unsigned int* hb = reinterpret_cast<unsigned int*>(hs);
    float* s0f = hs;                          // fp32 segs for h2 phase
    float* s1f = hs + 256;
    float* s2f = hs + 512;

    // ---------------- layers 1+2 fused, eight K-chunks of 64 ----------------
    float acc[8][NC];
    #pragma unroll
    for (int j = 0; j < 8; ++j)
        #pragma unroll
        for (int c = 0; c < NC; ++c) acc[j][c] = 0.0f;

    for (int ch = 0; ch < 8; ++ch) {
        // ---- layer 1: 4 neurons/lane -> 2 half2 slots (pair = k, k+16) ----
        #pragma unroll
        for (int q = 0; q < 2; ++q) {
            float jt0[NC], jt1[NC];
            l1jet<NA, NB, NC>(ch * 64 + g + 32 * q,      x_in, a_in, W1, b1, jt0);
            l1jet<NA, NB, NC>(ch * 64 + g + 32 * q + 16, x_in, a_in, W1, b1, jt1);
            unsigned int d[ST];
            #pragma unroll
            for (int c = 0; c < NC; ++c) d[c] = pkrtz(jt0[c], jt1[c]);
            #pragma unroll
            for (int c = NC; c < ST; ++c) d[c] = 0u;
            unsigned int* db = hb + (g + 16 * q) * ST;
            #pragma unroll
            for (int w4 = 0; w4 < ST / 4; ++w4) {
                uint4 v; v.x = d[4*w4]; v.y = d[4*w4+1]; v.z = d[4*w4+2]; v.w = d[4*w4+3];
                *reinterpret_cast<uint4*>(db + 4 * w4) = v;
            }
        }
        __syncthreads();

        // ---- layer 2 partial: 32 slots (64 k's), 8 outputs/lane, dot2 ----
        const unsigned int* __restrict__ Wp = W2p + ch * 4096 + 8 * g;
        #pragma unroll 1
        for (int sl0 = 0; sl0 < 32; sl0 += UNRS) {
            #pragma unroll
            for (int ss = 0; ss < UNRS; ++ss) {
                const int sl = sl0 + ss;
                const unsigned int* jb = hb + sl * ST;
                const uint4 ju0 = *reinterpret_cast<const uint4*>(jb);
                uint4 ju1; unsigned int ju2;
                if constexpr (NC > 4) ju1 = *reinterpret_cast<const uint4*>(jb + 4);
                if constexpr (NC > 8) ju2 = jb[8];
                const uint4 wu0 = *reinterpret_cast<const uint4*>(Wp + sl * 128);
                const uint4 wu1 = *reinterpret_cast<const uint4*>(Wp + sl * 128 + 4);

                half2_t jp[NC];
                jp[0] = __builtin_bit_cast(half2_t, ju0.x);
                if constexpr (NC > 1) jp[1] = __builtin_bit_cast(half2_t, ju0.y);
                if constexpr (NC > 2) jp[2] = __builtin_bit_cast(half2_t, ju0.z);
                if constexpr (NC > 3) jp[3] = __builtin_bit_cast(half2_t, ju0.w);
                if constexpr (NC > 4) jp[4] = __builtin_bit_cast(half2_t, ju1.x);
                if constexpr (NC > 5) jp[5] = __builtin_bit_cast(half2_t, ju1.y);
                if constexpr (NC > 6) jp[6] = __builtin_bit_cast(half2_t, ju1.z);
                if constexpr (NC > 7) jp[7] = __builtin_bit_cast(half2_t, ju1.w);
                if constexpr (NC > 8) jp[8] = __builtin_bit_cast(half2_t, ju2);

                half2_t wp[8];
                wp[0] = __builtin_bit_cast(half2_t, wu0.x);
                wp[1] = __builtin_bit_cast(half2_t, wu0.y);
                wp[2] = __builtin_bit_cast(half2_t, wu0.z);
                wp[3] = __builtin_bit_cast(half2_t, wu0.w);
                wp[4] = __builtin_bit_cast(half2_t, wu1.x);
                wp[5] = __builtin_bit_cast(half2_t, wu1.y);
                wp[6] = __builtin_bit_cast(half2_t, wu1.z);
                wp[7] = __builtin_bit_cast(half2_t, wu1.w);

                #pragma unroll
                for (int j = 0; j < 8; ++j)
                    #pragma unroll
                    for (int c = 0; c < NC; ++c)
                        acc[j][c] = dot2acc(wp[j], jp[c], acc[j][c]);
            }
        }
        __syncthreads();
    }

    // ------- layer-2 activation + layer 3, interleaved two-pass (fp32) -----
    // pass p (FULLY UNROLLED, rule #20): activate j=4p..4p+3 (n2=g+16j in
    // [64p,64p+64)), store fp32 h2 segs, then layer-3 over that half.
    float a3[4][NA], b3c[4][NB];
    #pragma unroll
    for (int j = 0; j < 4; ++j) {
        #pragma unroll
        for (int c = 0; c < NA; ++c) a3[j][c] = 0.0f;
        #pragma unroll
        for (int c = 0; c < NB; ++c) b3c[j][c] = 0.0f;
    }
    #pragma unroll
    for (int pass = 0; pass < 2; ++pass) {
        __syncthreads();                     // previous buffer reads done
        #pragma unroll
        for (int jj = 0; jj < 4; ++jj) {
            const int j  = 4 * pass + jj;
            const int n2 = g + 16 * j;
            const int idx = n2 - 64 * pass;  // 0..63
            float pj[NA], qj[NB], yj[NA], rj[NB];
            #pragma unroll
            for (int c = 0; c < NA; ++c) pj[c] = acc[j][2 * c];
            pj[0] += b2[n2];
            #pragma unroll
            for (int c = 0; c < NB; ++c) qj[c] = acc[j][2 * c + 1];
            tanh_jet<NA, NB>(pj, qj, yj, rj);
            float4 v0;
            v0.x = yj[0]; v0.y = rj[0]; v0.z = (NA >= 2) ? yj[1] : 0.0f;
            v0.w = (NB >= 2) ? rj[1] : 0.0f;
            *reinterpret_cast<float4*>(s0f + 4 * idx) = v0;
            if constexpr (NS4 == 2) {
                float4 v1;
                v1.x = yj[2]; v1.y = rj[2];
                v1.z = (NA >= 4) ? yj[3] : 0.0f;
                v1.w = (NB >= 4) ? rj[3] : 0.0f;
                *reinterpret_cast<float4*>(s1f + 4 * idx) = v1;
            }
            if constexpr (HAS2) {
                float2 v2; v2.x = yj[NA - 1]; v2.y = 0.0f;
                *reinterpret_cast<float2*>(s2f + 2 * idx) = v2;
            }
        }
        __syncthreads();

        const float* __restrict__ W3g = W3perm + pass * 4096 + 4 * g;
        #pragma unroll 1
        for (int k0 = 0; k0 < 64; k0 += UNR3) {
            #pragma unroll
            for (int kk = 0; kk < UNR3; ++kk) {
                const int k = k0 + kk;
                const float4 jv0 = *reinterpret_cast<const float4*>(s0f + 4 * k);
                float4 jv1; float2 jv2;
                if constexpr (NS4 == 2) jv1 = *reinterpret_cast<const float4*>(s1f + 4 * k);
                if constexpr (HAS2)     jv2 = *reinterpret_cast<const float2*>(s2f + 2 * k);
                const float4 wv4 = *reinterpret_cast<const float4*>(W3g + 64 * k);

                float ya[NA], za[NB];
                ya[0] = jv0.x; za[0] = jv0.y; ya[1] = jv0.z;
                if constexpr (NB >= 2) za[1] = jv0.w;
                if constexpr (NS4 == 2) {
                    ya[2] = jv1.x; za[2] = jv1.y;
                    if constexpr (NA >= 4) ya[3] = jv1.z;
                    if constexpr (NB >= 4) za[3] = jv1.w;
                }
                if constexpr (HAS2) ya[4] = jv2.x;
                const float w[4] = {wv4.x, wv4.y, wv4.z, wv4.w};
                #pragma unroll
                for (int j = 0; j < 4; ++j) {
                    #pragma unroll
                    for (int c = 0; c < NA; ++c)
                        a3[j][c] = fmaf(w[j], ya[c], a3[j][c]);
                    #pragma unroll
                    for (int c = 0; c < NB; ++c)
                        b3c[j][c] = fmaf(w[j], za[c], b3c[j][c]);
                }
            }
        }
    }

    // ---------------- layer 4 + loss (4 n3/lane, n3 = g + 16j) -------------
    float part[JS];
    #pragma unroll
    for (int c = 0; c < JS; ++c) part[c] = 0.0f;
    #pragma unroll
    for (int j = 0; j < 4; ++j) {
        const int n3 = g + 16 * j;
        float pj[NA], qj[NB], yj[NA], rj[NB];
        #pragma unroll
        for (int c = 0; c < NA; ++c) pj[c] = a3[j][c];
        pj[0] += b3[n3];
        #pragma unroll
        for (int c = 0; c < NB; ++c) qj[c] = b3c[j][c];
        tanh_jet<NA, NB>(pj, qj, yj, rj);
        const float w4 = W4[n3];
        #pragma unroll
        for (int c = 0; c < NA; ++c) part[c] = fmaf(w4, yj[c], part[c]);
        #pragma unroll
        for (int c = 0; c < NB; ++c) part[NA + c] = fmaf(w4, rj[c], part[NA + c]);
    }
    #pragma unroll
    for (int m = 1; m <= 8; m <<= 1)
        #pragma unroll
        for (int c = 0; c < JS; ++c)
            part[c] += __shfl_xor(part[c], m, 64);
    // all 16 lanes of each group now hold their sample's output jet

    const float A0 = part[0] + b4[0];
    float t0 = 0.0f, t1 = 0.0f, t2 = 0.0f;
    constexpr float CC = 1.0f;   // P/(E*I)
    if constexpr (TYPE == 0) {
        const float gx = 6.0f * part[NA + 3];
        const float ga = 24.0f * part[4] - gx;
        t0 = (gx + CC) * (gx + CC) + (ga + CC) * (ga + CC);
    }
    if constexpr (TYPE == 1) {
        t0 = A0 * A0;
        const float gx = part[NA + 0];
        const float ga = part[1] - gx;
        t1 = gx * gx + ga * ga;
    }
    if constexpr (TYPE == 2) {
        const float wa = a_in * A0;
        t0 = wa * wa;
        const float g2x = part[NA + 1];
        const float g2a = 2.0f * part[2] - g2x;
        t1 = g2x * g2x + g2a * g2a;
        const float g3x = 2.0f * part[NA + 2];
        const float g3a = 6.0f * part[3] - g3x;
        const float om = 1.0f - a_in;
        t2 = om * om * (g3x * g3x + g3a * g3a);
    }
    if (!valid) { t0 = 0.0f; t1 = 0.0f; t2 = 0.0f; }

    // sum the wave's 4 samples (cross-group butterflies)
    t0 += __shfl_xor(t0, 16, 64); t0 += __shfl_xor(t0, 32, 64);
    if constexpr (TYPE != 0) { t1 += __shfl_xor(t1, 16, 64); t1 += __shfl_xor(t1, 32, 64); }
    if constexpr (TYPE == 2) { t2 += __shfl_xor(t2, 16, 64); t2 += __shfl_xor(t2, 32, 64); }

    if (t == 0) {
        if constexpr (TYPE == 0) {
            ws[bi] = t0;
        } else if constexpr (TYPE == 1) {
            ws[NB0 + bi]     = t0;
            ws[2 * NB0 + bi] = t1;
        } else {
            ws[3 * NB0 + bi] = t0;
            ws[4 * NB0 + bi] = t1;
            ws[5 * NB0 + bi] = t2;
        }
    }
}

__global__ __launch_bounds__(64, 2)
void pinn_fat(const float* __restrict__ inp,
              const float* __restrict__ W1, const float* __restrict__ b1,
              const unsigned int* __restrict__ W2p, const float* __restrict__ b2,
              const float* __restrict__ W3perm, const float* __restrict__ b3,
              const float* __restrict__ W4, const float* __restrict__ b4,
              float* __restrict__ ws, int N, int NB0)
{
    __shared__ __align__(16) float h[4 * SSTR];    // 10368 B
    const int b = blockIdx.x;
    if (b < NB0)
        eval_body<5, 4, 0>(b, inp, W1, b1, W2p, b2, W3perm, b3, W4, b4, ws, N, NB0, h);
    else if (b < 2 * NB0)
        eval_body<4, 3, 2>(b - NB0, inp, W1, b1, W2p, b2, W3perm, b3, W4, b4, ws, N, NB0, h);
    else
        eval_body<2, 1, 1>(b - 2 * NB0, inp, W1, b1, W2p, b2, W3perm, b3, W4, b4, ws, N, NB0, h);
}

__global__ __launch_bounds__(1024)
void pinn_reduce(const float* __restrict__ ws, float* __restrict__ out,
                 int G, float invN, float inv2N)
{
    __shared__ float sh[16 * 6];
    float s[6];
    #pragma unroll
    for (int q = 0; q < 6; ++q) {
        float acc = 0.0f;
        for (int i = threadIdx.x; i < G; i += 1024) acc += ws[q * G + i];
        #pragma unroll
        for (int m = 1; m <= 32; m <<= 1) acc += __shfl_xor(acc, m, 64);
        s[q] = acc;
    }
    const int wid = threadIdx.x >> 6;
    if ((threadIdx.x & 63) == 0) {
        #pragma unroll
        for (int q = 0; q < 6; ++q) sh[wid * 6 + q] = s[q];
    }
    __syncthreads();
    if (threadIdx.x == 0) {
        float r[6];
        #pragma unroll
        for (int q = 0; q < 6; ++q) {
            float acc = 0.0f;
            for (int w = 0; w < 16; ++w) acc += sh[w * 6 + q];
            r[q] = acc;
        }
        const float pde   = r[0] * inv2N;
        const float w0    = r[1] * invN;
        const float w0x   = r[2] * inv2N;
        const float wL    = r[3] * invN;
        const float wLxx  = r[4] * inv2N;
        const float wLxxx = r[5] * inv2N;
        out[0] = pde + w0 + w0x + wL + wLxx + wLxxx;
        out[1] = pde;
        out[2] = w0;
        out[3] = w0x;
        out[4] = wL;
        out[5] = wLxx;
        out[6] = wLxxx;
    }
}

extern "C" void kernel_launch(void* const* d_in, const int* in_sizes, int n_in,
                              void* d_out, int out_size, void* d_ws, size_t ws_size,
                              hipStream_t stream) {
    const float* inp = (const float*)d_in[0];
    const float* W1  = (const float*)d_in[1];
    const float* b1  = (const float*)d_in[2];
    const float* W2  = (const float*)d_in[3];
    const float* b2  = (const float*)d_in[4];
    const float* W3  = (const float*)d_in[5];
    const float* b3  = (const float*)d_in[6];
    const float* W4  = (const float*)d_in[7];
    const float* b4  = (const float*)d_in[8];
    float* ws  = (float*)d_ws;
    float* out = (float*)d_out;

    const int N   = in_sizes[0] / 2;   // 32768
    const int NB0 = (N + 3) / 4;       // blocks per eval type (4 samples/block)

    // pair+fp16 W2 and permute W3 (into d_ws)
    pinn_prep<<<dim3(128), dim3(256), 0, stream>>>(W2, W3, ws);

    pinn_fat<<<dim3(3 * NB0), dim3(64), 0, stream>>>(
        inp, W1, b1, reinterpret_cast<const unsigned int*>(ws) + OFF_W2U, b2,
        ws + OFF_W3F, b3, W4, b4, ws, N, NB0);
    pinn_reduce<<<dim3(1), dim3(1024), 0, stream>>>(
        ws, out, NB0, 1.0f / (float)N, 0.5f / (float)N);
}

// Round 13
// 169.695 us; speedup vs baseline: 16.9140x; 4.9748x over previous
//
#include <hip/hip_runtime.h>
#include <math.h>

// ---------------------------------------------------------------------------
// PINN beam loss via forward-mode bivariate jets (v13: MFMA layers 2+3).
// Jet of f(z + t*(1,1) + s*(1,0)):  y[k]=coeff t^k, z[k]=coeff t^k s.
// Layer-1: pre-act = p0 + d*t + wx*s  =>  z[k] = (k+1)*(wx/d)*y[k+1] exactly.
//
// Block = 256 threads (4 waves) = 16 samples. Layer 2 runs as NC separate
// 16x16x32-f16 MFMA GEMMs (one per jet component):
//   D_c[128 n2][16 samples] = W2^T[128][512] * H1_c[512][16]
// D layout (m89): col=lane&15=sample, row=(lane>>4)*4+r  => all NC comps of a
// (sample, n2) land in ONE lane -> tanh_jet stays lane-local, no shuffles.
// K chunked 8x64: layer-1 produces fp16 jets into LDS B-layout [NC][16][72],
// A = pre-transposed fp16 W2t/W3t (prep kernel, L2-resident).
// Fragment bet: A/B lane holds 8 CONTIGUOUS k at k=(l>>4)*8 (m92 refcheck'd
// contiguous bf16x8 fragment loads support this).
// Layer 3 same pattern (M=64, K=128 via 2 store/mfma passes reusing LDS).
// ---------------------------------------------------------------------------

typedef _Float16 half8 __attribute__((ext_vector_type(8)));
typedef float f32x4 __attribute__((ext_vector_type(4)));

#define W2T_HOFF 32768     // half-offset of W2t[128][512] in ws (byte 65536)
#define W3T_HOFF 98304     // half-offset of W3t[64][128]  in ws (byte 196608)

__device__ __forceinline__ unsigned int pkrtz(float lo, float hi) {
    return __builtin_bit_cast(unsigned int, __builtin_amdgcn_cvt_pkrtz(lo, hi));
}

__device__ __forceinline__ float fast_tanh(float x) {
    float ax = fabsf(x);
    float e  = __expf(-2.0f * ax);
    float y  = (1.0f - e) * __builtin_amdgcn_rcpf(1.0f + e);
    return copysignf(y, x);
}

template<int NA, int NB>
__device__ __forceinline__ void tanh_jet(const float (&p)[NA], const float (&q)[NB],
                                         float (&y)[NA], float (&r)[NB]) {
    constexpr int NU = ((NA - 1) > NB ? (NA - 1) : NB);
    float u[NU];
    y[0] = fast_tanh(p[0]);
    u[0] = fmaf(-y[0], y[0], 1.0f);
    if constexpr (NA >= 2) y[1] = u[0] * p[1];
    if constexpr (NU >= 2) u[1] = -2.0f * y[0] * y[1];
    if constexpr (NA >= 3) y[2] = fmaf(u[0], p[2], 0.5f * u[1] * p[1]);
    if constexpr (NU >= 3) u[2] = -fmaf(2.0f * y[0], y[2], y[1] * y[1]);
    if constexpr (NA >= 4) y[3] = fmaf(u[0], p[3], fmaf((2.0f/3.0f) * u[1], p[2],
                                       (1.0f/3.0f) * u[2] * p[1]));
    if constexpr (NU >= 4) u[3] = -2.0f * fmaf(y[0], y[3], y[1] * y[2]);
    if constexpr (NA >= 5) y[4] = fmaf(u[0], p[4], fmaf(0.75f * u[1], p[3],
                                       fmaf(0.5f * u[2], p[2], 0.25f * u[3] * p[1])));
    #pragma unroll
    for (int k = 0; k < NB; ++k) {
        float s = 0.0f;
        #pragma unroll
        for (int j = 0; j <= k; ++j) s = fmaf(u[j], q[k - j], s);
        r[k] = s;
    }
}

// layer-1 jet of neuron nn, interleaved [y0,z0,y1,z1,...,y_{NB-1},z_{NB-1},y_{NA-1}]
template<int NA, int NB, int NC>
__device__ __forceinline__ void l1jet(int nn, float x_in, float a_in,
                                      const float* __restrict__ W1,
                                      const float* __restrict__ b1,
                                      float (&jt)[NC]) {
    const float wx = W1[nn];
    const float wa = W1[512 + nn];
    float d = wx + wa;
    if (d == 0.0f) d = 1e-30f;
    const float p0 = fmaf(wx, x_in, fmaf(wa, a_in, b1[nn]));
    const float y0 = fast_tanh(p0);
    const float u0 = fmaf(-y0, y0, 1.0f);
    const float e  = wx * __builtin_amdgcn_rcpf(d);
    float y1 = 0.0f, y2 = 0.0f, y3 = 0.0f, y4 = 0.0f;
    if constexpr (NA >= 2) y1 = u0 * d;
    if constexpr (NA >= 3) { const float u1 = -2.0f * y0 * y1; y2 = 0.5f * u1 * d; }
    if constexpr (NA >= 4) { const float u2 = -fmaf(2.0f * y0, y2, y1 * y1);
                             y3 = (1.0f/3.0f) * u2 * d; }
    if constexpr (NA >= 5) { const float u3 = -2.0f * fmaf(y0, y3, y1 * y2);
                             y4 = 0.25f * u3 * d; }
    jt[0] = y0;
    jt[1] = e * y1;
    if constexpr (NB >= 2) { jt[2] = y1; jt[3] = 2.0f * e * y2; }
    if constexpr (NB >= 3) { jt[4] = y2; jt[5] = 3.0f * e * y3; }
    if constexpr (NB >= 4) { jt[6] = y3; jt[7] = 4.0f * e * y4; }
    if constexpr (NA == 2) jt[2 * NB] = y1;
    else if constexpr (NA == 3) jt[2 * NB] = y2;
    else if constexpr (NA == 4) jt[2 * NB] = y3;
    else                        jt[2 * NB] = y4;
}

// Transpose + fp16-convert the weights: W2t[n][k] = W2[k][n], W3t[n][k] = W3[k][n]
__global__ __launch_bounds__(256)
void pinn_prep(const float* __restrict__ W2, const float* __restrict__ W3,
               _Float16* __restrict__ wsh)
{
    const int i = blockIdx.x * 256 + threadIdx.x;
    if (i < 65536) {
        const int n = i >> 9, k = i & 511;
        wsh[W2T_HOFF + i] = (_Float16)W2[k * 128 + n];
    }
    if (i < 8192) {
        const int n = i >> 7, k = i & 127;
        wsh[W3T_HOFF + i] = (_Float16)W3[k * 64 + n];
    }
}

template<int NA, int NB, int TYPE>
__device__ __forceinline__ void eval_body(
    int bi, const float* __restrict__ inp,
    const float* __restrict__ W1, const float* __restrict__ b1,
    const _Float16* __restrict__ W2t, const float* __restrict__ b2,
    const _Float16* __restrict__ W3t, const float* __restrict__ b3,
    const float* __restrict__ W4, const float* __restrict__ b4,
    float* __restrict__ ws, int N, int nbx,
    _Float16* __restrict__ hbuf, float (*red)[16][9])
{
    constexpr int NC = NA + NB;              // 9 / 7 / 3 jet components

    const int t    = threadIdx.x;            // 0..255
    const int l    = t & 63;
    const int w    = t >> 6;                 // wave 0..3
    const int col  = l & 15;                 // MFMA N-col = sample
    const int rgrp = l >> 4;                 // 0..3
    const int kb   = rgrp * 8;               // fragment k base (contiguous-8 bet)

    // layer-1 production mapping: sample = t&15, k-local base = (t>>4)*4
    const int s1   = t & 15;
    const int klb  = (t >> 4) * 4;
    const int i1   = bi * 16 + s1;
    const int ii   = (i1 < N) ? i1 : (N - 1);
    const float a1 = inp[2 * ii + 1];
    float x1;
    if constexpr (TYPE == 0)      x1 = inp[2 * ii + 0];
    else if constexpr (TYPE == 1) x1 = 0.0f;
    else                          x1 = 1.0f;

    unsigned int* hb32 = reinterpret_cast<unsigned int*>(hbuf);

    // ---------------- layers 1+2 fused: 8 K-chunks of 64 ----------------
    f32x4 acc0[NC], acc1[NC];
    #pragma unroll
    for (int c = 0; c < NC; ++c) { acc0[c] = (f32x4)0.0f; acc1[c] = (f32x4)0.0f; }

    const _Float16* A0b = W2t + ((2 * w) * 16 + col) * 512;
    const _Float16* A1b = W2t + ((2 * w + 1) * 16 + col) * 512;

    for (int ch = 0; ch < 8; ++ch) {
        // ---- layer 1: 4 jets/thread -> packed fp16 pairs into LDS B-layout
        #pragma unroll
        for (int pr = 0; pr < 2; ++pr) {
            float j0[NC], j1[NC];
            l1jet<NA, NB, NC>(ch * 64 + klb + 2 * pr,     x1, a1, W1, b1, j0);
            l1jet<NA, NB, NC>(ch * 64 + klb + 2 * pr + 1, x1, a1, W1, b1, j1);
            #pragma unroll
            for (int c = 0; c < NC; ++c)
                hb32[(c * 16 + s1) * 36 + (klb >> 1) + pr] = pkrtz(j0[c], j1[c]);
        }
        __syncthreads();

        // ---- layer 2: 2 K-steps x NC comps, 2 row-tiles per wave ----
        #pragma unroll
        for (int ks = 0; ks < 2; ++ks) {
            const int kg = ch * 64 + ks * 32 + kb;
            const half8 A0 = *reinterpret_cast<const half8*>(A0b + kg);
            const half8 A1 = *reinterpret_cast<const half8*>(A1b + kg);
            #pragma unroll
            for (int c = 0; c < NC; ++c) {
                const half8 B = *reinterpret_cast<const half8*>(
                    hbuf + (c * 16 + col) * 72 + ks * 32 + kb);
                acc0[c] = __builtin_amdgcn_mfma_f32_16x16x32_f16(A0, B, acc0[c], 0, 0, 0);
                acc1[c] = __builtin_amdgcn_mfma_f32_16x16x32_f16(A1, B, acc1[c], 0, 0, 0);
            }
        }
        __syncthreads();
    }

    // ---------------- layer-2 activation (lane-local, in place) ------------
    // lane holds n2 = tile*16 + rgrp*4 + r for tiles {2w, 2w+1}, sample = col.
    {
        const float* b2p0 = b2 + (2 * w) * 16 + rgrp * 4;
        const float* b2p1 = b2 + (2 * w + 1) * 16 + rgrp * 4;
        #pragma unroll
        for (int r = 0; r < 4; ++r) {
            {
                float pj[NA], qj[NB], yj[NA], rj[NB];
                #pragma unroll
                for (int j = 0; j < NA; ++j) pj[j] = acc0[2 * j][r];
                #pragma unroll
                for (int j = 0; j < NB; ++j) qj[j] = acc0[2 * j + 1][r];
                pj[0] += b2p0[r];
                tanh_jet<NA, NB>(pj, qj, yj, rj);
                #pragma unroll
                for (int j = 0; j < NA; ++j) acc0[2 * j][r] = yj[j];
                #pragma unroll
                for (int j = 0; j < NB; ++j) acc0[2 * j + 1][r] = rj[j];
            }
            {
                float pj[NA], qj[NB], yj[NA], rj[NB];
                #pragma unroll
                for (int j = 0; j < NA; ++j) pj[j] = acc1[2 * j][r];
                #pragma unroll
                for (int j = 0; j < NB; ++j) qj[j] = acc1[2 * j + 1][r];
                pj[0] += b2p1[r];
                tanh_jet<NA, NB>(pj, qj, yj, rj);
                #pragma unroll
                for (int j = 0; j < NA; ++j) acc1[2 * j][r] = yj[j];
                #pragma unroll
                for (int j = 0; j < NB; ++j) acc1[2 * j + 1][r] = rj[j];
            }
        }
    }

    // ---------------- layer 3: two store/mfma passes over K=128 ------------
    f32x4 acc3[NC];
    #pragma unroll
    for (int c = 0; c < NC; ++c) acc3[c] = (f32x4)0.0f;
    const _Float16* A3b = W3t + (w * 16 + col) * 128;

    #pragma unroll
    for (int pass = 0; pass < 2; ++pass) {
        __syncthreads();                     // prior B reads complete
        if ((w >> 1) == pass) {              // waves owning rows [64p,64p+64)
            const int base0 = (w & 1) * 32 + rgrp * 4;        // tile 2w
            const int base1 = base0 + 16;                     // tile 2w+1
            #pragma unroll
            for (int c = 0; c < NC; ++c) {
                hb32[(c * 16 + col) * 36 + (base0 >> 1)]     = pkrtz(acc0[c][0], acc0[c][1]);
                hb32[(c * 16 + col) * 36 + (base0 >> 1) + 1] = pkrtz(acc0[c][2], acc0[c][3]);
                hb32[(c * 16 + col) * 36 + (base1 >> 1)]     = pkrtz(acc1[c][0], acc1[c][1]);
                hb32[(c * 16 + col) * 36 + (base1 >> 1) + 1] = pkrtz(acc1[c][2], acc1[c][3]);
            }
        }
        __syncthreads();
        #pragma unroll
        for (int ks = 0; ks < 2; ++ks) {
            const int kg = pass * 64 + ks * 32 + kb;
            const half8 A3 = *reinterpret_cast<const half8*>(A3b + kg);
            #pragma unroll
            for (int c = 0; c < NC; ++c) {
                const half8 B = *reinterpret_cast<const half8*>(
                    hbuf + (c * 16 + col) * 72 + ks * 32 + kb);
                acc3[c] = __builtin_amdgcn_mfma_f32_16x16x32_f16(A3, B, acc3[c], 0, 0, 0);
            }
        }
    }

    // ---------------- layer 4 + loss ----------------
    // lane holds n3 = w*16 + rgrp*4 + r, sample = col.
    float part[NC];
    #pragma unroll
    for (int c = 0; c < NC; ++c) part[c] = 0.0f;
    {
        const float* b3p = b3 + w * 16 + rgrp * 4;
        const float* w4p = W4 + w * 16 + rgrp * 4;
        #pragma unroll
        for (int r = 0; r < 4; ++r) {
            float pj[NA], qj[NB], yj[NA], rj[NB];
            #pragma unroll
            for (int j = 0; j < NA; ++j) pj[j] = acc3[2 * j][r];
            #pragma unroll
            for (int j = 0; j < NB; ++j) qj[j] = acc3[2 * j + 1][r];
            pj[0] += b3p[r];
            tanh_jet<NA, NB>(pj, qj, yj, rj);
            const float w4 = w4p[r];
            #pragma unroll
            for (int c = 0; c < NA; ++c) part[c] = fmaf(w4, yj[c], part[c]);
            #pragma unroll
            for (int c = 0; c < NB; ++c) part[NA + c] = fmaf(w4, rj[c], part[NA + c]);
        }
    }
    // reduce over the 4 row-groups of the wave
    #pragma unroll
    for (int c = 0; c < NC; ++c) {
        part[c] += __shfl_xor(part[c], 16, 64);
        part[c] += __shfl_xor(part[c], 32, 64);
    }
    if (l < 16) {
        #pragma unroll
        for (int c = 0; c < NC; ++c) red[w][l][c] = part[c];
    }
    __syncthreads();

    if (t < 16) {
        float pp[NC];
        #pragma unroll
        for (int c = 0; c < NC; ++c)
            pp[c] = red[0][t][c] + red[1][t][c] + red[2][t][c] + red[3][t][c];
        const int is = bi * 16 + t;
        const bool valid = (is < N);
        const float a_s = inp[2 * ((is < N) ? is : (N - 1)) + 1];
        const float A0v = pp[0] + b4[0];
        float t0 = 0.0f, t1 = 0.0f, t2 = 0.0f;
        constexpr float CC = 1.0f;   // P/(E*I)
        if constexpr (TYPE == 0) {
            const float gx = 6.0f * pp[NA + 3];
            const float ga = 24.0f * pp[4] - gx;
            t0 = (gx + CC) * (gx + CC) + (ga + CC) * (ga + CC);
        }
        if constexpr (TYPE == 1) {
            t0 = A0v * A0v;
            const float gx = pp[NA + 0];
            const float ga = pp[1] - gx;
            t1 = gx * gx + ga * ga;
        }
        if constexpr (TYPE == 2) {
            const float wa = a_s * A0v;
            t0 = wa * wa;
            const float g2x = pp[NA + 1];
            const float g2a = 2.0f * pp[2] - g2x;
            t1 = g2x * g2x + g2a * g2a;
            const float g3x = 2.0f * pp[NA + 2];
            const float g3a = 6.0f * pp[3] - g3x;
            const float om = 1.0f - a_s;
            t2 = om * om * (g3x * g3x + g3a * g3a);
        }
        if (!valid) { t0 = 0.0f; t1 = 0.0f; t2 = 0.0f; }
        #pragma unroll
        for (int m = 1; m <= 8; m <<= 1) {
            t0 += __shfl_xor(t0, m, 64);
            if constexpr (TYPE != 0) t1 += __shfl_xor(t1, m, 64);
            if constexpr (TYPE == 2) t2 += __shfl_xor(t2, m, 64);
        }
        if (t == 0) {
            if constexpr (TYPE == 0) {
                ws[bi] = t0;
            } else if constexpr (TYPE == 1) {
                ws[nbx + bi]     = t0;
                ws[2 * nbx + bi] = t1;
            } else {
                ws[3 * nbx + bi] = t0;
                ws[4 * nbx + bi] = t1;
                ws[5 * nbx + bi] = t2;
            }
        }
    }
}

__global__ __launch_bounds__(256, 2)
void pinn_fat(const float* __restrict__ inp,
              const float* __restrict__ W1, const float* __restrict__ b1,
              const _Float16* __restrict__ W2t, const float* __restrict__ b2,
              const _Float16* __restrict__ W3t, const float* __restrict__ b3,
              const float* __restrict__ W4, const float* __restrict__ b4,
              float* __restrict__ ws, int N, int nbx)
{
    __shared__ __align__(16) _Float16 hbuf[10368];   // [9][16][72] = 20736 B
    __shared__ float red[4][16][9];                  // 2304 B
    const int b = blockIdx.x;
    if (b < nbx)
        eval_body<5, 4, 0>(b, inp, W1, b1, W2t, b2, W3t, b3, W4, b4, ws, N, nbx, hbuf, red);
    else if (b < 2 * nbx)
        eval_body<4, 3, 2>(b - nbx, inp, W1, b1, W2t, b2, W3t, b3, W4, b4, ws, N, nbx, hbuf, red);
    else
        eval_body<2, 1, 1>(b - 2 * nbx, inp, W1, b1, W2t, b2, W3t, b3, W4, b4, ws, N, nbx, hbuf, red);
}

__global__ __launch_bounds__(1024)
void pinn_reduce(const float* __restrict__ ws, float* __restrict__ out,
                 int G, float invN, float inv2N)
{
    __shared__ float sh[16 * 6];
    float s[6];
    #pragma unroll
    for (int q = 0; q < 6; ++q) {
        float acc = 0.0f;
        for (int i = threadIdx.x; i < G; i += 1024) acc += ws[q * G + i];
        #pragma unroll
        for (int m = 1; m <= 32; m <<= 1) acc += __shfl_xor(acc, m, 64);
        s[q] = acc;
    }
    const int wid = threadIdx.x >> 6;
    if ((threadIdx.x & 63) == 0) {
        #pragma unroll
        for (int q = 0; q < 6; ++q) sh[wid * 6 + q] = s[q];
    }
    __syncthreads();
    if (threadIdx.x == 0) {
        float r[6];
        #pragma unroll
        for (int q = 0; q < 6; ++q) {
            float acc = 0.0f;
            for (int w = 0; w < 16; ++w) acc += sh[w * 6 + q];
            r[q] = acc;
        }
        const float pde   = r[0] * inv2N;
        const float w0    = r[1] * invN;
        const float w0x   = r[2] * inv2N;
        const float wL    = r[3] * invN;
        const float wLxx  = r[4] * inv2N;
        const float wLxxx = r[5] * inv2N;
        out[0] = pde + w0 + w0x + wL + wLxx + wLxxx;
        out[1] = pde;
        out[2] = w0;
        out[3] = w0x;
        out[4] = wL;
        out[5] = wLxx;
        out[6] = wLxxx;
    }
}

extern "C" void kernel_launch(void* const* d_in, const int* in_sizes, int n_in,
                              void* d_out, int out_size, void* d_ws, size_t ws_size,
                              hipStream_t stream) {
    const float* inp = (const float*)d_in[0];
    const float* W1  = (const float*)d_in[1];
    const float* b1  = (const float*)d_in[2];
    const float* W2  = (const float*)d_in[3];
    const float* b2  = (const float*)d_in[4];
    const float* W3  = (const float*)d_in[5];
    const float* b3  = (const float*)d_in[6];
    const float* W4  = (const float*)d_in[7];
    const float* b4  = (const float*)d_in[8];
    float* ws  = (float*)d_ws;
    _Float16* wsh = (_Float16*)d_ws;
    float* out = (float*)d_out;

    const int N   = in_sizes[0] / 2;   // 32768
    const int nbx = (N + 15) / 16;     // blocks per eval type (16 samples/block)

    // transpose + fp16 weights into ws (bytes 65536..212992)
    pinn_prep<<<dim3(256), dim3(256), 0, stream>>>(W2, W3, wsh);

    pinn_fat<<<dim3(3 * nbx), dim3(256), 0, stream>>>(
        inp, W1, b1, wsh + W2T_HOFF, b2, wsh + W3T_HOFF, b3, W4, b4, ws, N, nbx);
    pinn_reduce<<<dim3(1), dim3(1024), 0, stream>>>(
        ws, out, nbx, 1.0f / (float)N, 0.5f / (float)N);
}

// Round 14
// 166.273 us; speedup vs baseline: 17.2621x; 1.0206x over previous
//
#include <hip/hip_runtime.h>
#include <math.h>

// ---------------------------------------------------------------------------
// PINN beam loss via forward-mode bivariate jets (v14 = v13 + dbuf overlap).
// Jet of f(z + t*(1,1) + s*(1,0)):  y[k]=coeff t^k, z[k]=coeff t^k s.
// Layer-1: pre-act = p0 + d*t + wx*s  =>  z[k] = (k+1)*(wx/d)*y[k+1] exactly.
//
// Block = 256 threads (4 waves) = 16 samples. Layer 2 runs as NC separate
// 16x16x32-f16 MFMA GEMMs (one per jet component); D layout (m89):
// col=lane&15=sample, row=(lane>>4)*4+r -> tanh_jet stays lane-local.
// v14 change: jet LDS is DOUBLE-BUFFERED; chunk ch+1 is produced in the same
// inter-barrier region as chunk ch's MFMAs (one barrier per chunk, was two).
// Waves drift within the region -> one wave's l1jet VALU overlaps another's
// MFMA issue (m114 co-schedule). v13 was phase-serialization-bound
// (MfmaUtil 21, VALUBusy 45, neither saturated).
// ---------------------------------------------------------------------------

typedef _Float16 half8 __attribute__((ext_vector_type(8)));
typedef float f32x4 __attribute__((ext_vector_type(4)));

#define W2T_HOFF 32768     // half-offset of W2t[128][512] in ws (byte 65536)
#define W3T_HOFF 98304     // half-offset of W3t[64][128]  in ws (byte 196608)

__device__ __forceinline__ unsigned int pkrtz(float lo, float hi) {
    return __builtin_bit_cast(unsigned int, __builtin_amdgcn_cvt_pkrtz(lo, hi));
}

__device__ __forceinline__ float fast_tanh(float x) {
    float ax = fabsf(x);
    float e  = __expf(-2.0f * ax);
    float y  = (1.0f - e) * __builtin_amdgcn_rcpf(1.0f + e);
    return copysignf(y, x);
}

template<int NA, int NB>
__device__ __forceinline__ void tanh_jet(const float (&p)[NA], const float (&q)[NB],
                                         float (&y)[NA], float (&r)[NB]) {
    constexpr int NU = ((NA - 1) > NB ? (NA - 1) : NB);
    float u[NU];
    y[0] = fast_tanh(p[0]);
    u[0] = fmaf(-y[0], y[0], 1.0f);
    if constexpr (NA >= 2) y[1] = u[0] * p[1];
    if constexpr (NU >= 2) u[1] = -2.0f * y[0] * y[1];
    if constexpr (NA >= 3) y[2] = fmaf(u[0], p[2], 0.5f * u[1] * p[1]);
    if constexpr (NU >= 3) u[2] = -fmaf(2.0f * y[0], y[2], y[1] * y[1]);
    if constexpr (NA >= 4) y[3] = fmaf(u[0], p[3], fmaf((2.0f/3.0f) * u[1], p[2],
                                       (1.0f/3.0f) * u[2] * p[1]));
    if constexpr (NU >= 4) u[3] = -2.0f * fmaf(y[0], y[3], y[1] * y[2]);
    if constexpr (NA >= 5) y[4] = fmaf(u[0], p[4], fmaf(0.75f * u[1], p[3],
                                       fmaf(0.5f * u[2], p[2], 0.25f * u[3] * p[1])));
    #pragma unroll
    for (int k = 0; k < NB; ++k) {
        float s = 0.0f;
        #pragma unroll
        for (int j = 0; j <= k; ++j) s = fmaf(u[j], q[k - j], s);
        r[k] = s;
    }
}

// layer-1 jet of neuron nn, interleaved [y0,z0,y1,z1,...,y_{NB-1},z_{NB-1},y_{NA-1}]
template<int NA, int NB, int NC>
__device__ __forceinline__ void l1jet(int nn, float x_in, float a_in,
                                      const float* __restrict__ W1,
                                      const float* __restrict__ b1,
                                      float (&jt)[NC]) {
    const float wx = W1[nn];
    const float wa = W1[512 + nn];
    float d = wx + wa;
    if (d == 0.0f) d = 1e-30f;
    const float p0 = fmaf(wx, x_in, fmaf(wa, a_in, b1[nn]));
    const float y0 = fast_tanh(p0);
    const float u0 = fmaf(-y0, y0, 1.0f);
    const float e  = wx * __builtin_amdgcn_rcpf(d);
    float y1 = 0.0f, y2 = 0.0f, y3 = 0.0f, y4 = 0.0f;
    if constexpr (NA >= 2) y1 = u0 * d;
    if constexpr (NA >= 3) { const float u1 = -2.0f * y0 * y1; y2 = 0.5f * u1 * d; }
    if constexpr (NA >= 4) { const float u2 = -fmaf(2.0f * y0, y2, y1 * y1);
                             y3 = (1.0f/3.0f) * u2 * d; }
    if constexpr (NA >= 5) { const float u3 = -2.0f * fmaf(y0, y3, y1 * y2);
                             y4 = 0.25f * u3 * d; }
    jt[0] = y0;
    jt[1] = e * y1;
    if constexpr (NB >= 2) { jt[2] = y1; jt[3] = 2.0f * e * y2; }
    if constexpr (NB >= 3) { jt[4] = y2; jt[5] = 3.0f * e * y3; }
    if constexpr (NB >= 4) { jt[6] = y3; jt[7] = 4.0f * e * y4; }
    if constexpr (NA == 2) jt[2 * NB] = y1;
    else if constexpr (NA == 3) jt[2 * NB] = y2;
    else if constexpr (NA == 4) jt[2 * NB] = y3;
    else                        jt[2 * NB] = y4;
}

// produce one 64-k chunk of fp16 jet pairs into the given LDS buffer
template<int NA, int NB, int NC>
__device__ __forceinline__ void produce_chunk(
    int ch, unsigned int* __restrict__ hb32, int s1, int klb,
    float x1, float a1, const float* __restrict__ W1, const float* __restrict__ b1)
{
    #pragma unroll
    for (int pr = 0; pr < 2; ++pr) {
        float j0[NC], j1[NC];
        l1jet<NA, NB, NC>(ch * 64 + klb + 2 * pr,     x1, a1, W1, b1, j0);
        l1jet<NA, NB, NC>(ch * 64 + klb + 2 * pr + 1, x1, a1, W1, b1, j1);
        #pragma unroll
        for (int c = 0; c < NC; ++c)
            hb32[(c * 16 + s1) * 36 + (klb >> 1) + pr] = pkrtz(j0[c], j1[c]);
    }
}

// Transpose + fp16-convert the weights: W2t[n][k] = W2[k][n], W3t[n][k] = W3[k][n]
__global__ __launch_bounds__(256)
void pinn_prep(const float* __restrict__ W2, const float* __restrict__ W3,
               _Float16* __restrict__ wsh)
{
    const int i = blockIdx.x * 256 + threadIdx.x;
    if (i < 65536) {
        const int n = i >> 9, k = i & 511;
        wsh[W2T_HOFF + i] = (_Float16)W2[k * 128 + n];
    }
    if (i < 8192) {
        const int n = i >> 7, k = i & 127;
        wsh[W3T_HOFF + i] = (_Float16)W3[k * 64 + n];
    }
}

template<int NA, int NB, int TYPE>
__device__ __forceinline__ void eval_body(
    int bi, const float* __restrict__ inp,
    const float* __restrict__ W1, const float* __restrict__ b1,
    const _Float16* __restrict__ W2t, const float* __restrict__ b2,
    const _Float16* __restrict__ W3t, const float* __restrict__ b3,
    const float* __restrict__ W4, const float* __restrict__ b4,
    float* __restrict__ ws, int N, int nbx,
    _Float16* __restrict__ hbuf0, _Float16* __restrict__ hbuf1,
    float (*red)[16][9])
{
    constexpr int NC = NA + NB;              // 9 / 7 / 3 jet components

    const int t    = threadIdx.x;            // 0..255
    const int l    = t & 63;
    const int w    = t >> 6;                 // wave 0..3
    const int col  = l & 15;                 // MFMA N-col = sample
    const int rgrp = l >> 4;                 // 0..3
    const int kb   = rgrp * 8;               // fragment k base (contiguous 8)

    // layer-1 production mapping: sample = t&15, k-local base = (t>>4)*4
    const int s1   = t & 15;
    const int klb  = (t >> 4) * 4;
    const int i1   = bi * 16 + s1;
    const int ii   = (i1 < N) ? i1 : (N - 1);
    const float a1 = inp[2 * ii + 1];
    float x1;
    if constexpr (TYPE == 0)      x1 = inp[2 * ii + 0];
    else if constexpr (TYPE == 1) x1 = 0.0f;
    else                          x1 = 1.0f;

    unsigned int* hb0 = reinterpret_cast<unsigned int*>(hbuf0);
    unsigned int* hb1 = reinterpret_cast<unsigned int*>(hbuf1);

    // ---------------- layers 1+2 fused: 8 K-chunks of 64, double-buffered --
    f32x4 acc0[NC], acc1[NC];
    #pragma unroll
    for (int c = 0; c < NC; ++c) { acc0[c] = (f32x4)0.0f; acc1[c] = (f32x4)0.0f; }

    const _Float16* A0b = W2t + ((2 * w) * 16 + col) * 512;
    const _Float16* A1b = W2t + ((2 * w + 1) * 16 + col) * 512;

    produce_chunk<NA, NB, NC>(0, hb0, s1, klb, x1, a1, W1, b1);
    __syncthreads();

    for (int ch = 0; ch < 8; ++ch) {
        unsigned int*   hbN = (ch & 1) ? hb0 : hb1;       // next (produce)
        const _Float16* hfC = (ch & 1) ? hbuf1 : hbuf0;   // current (consume)

        if (ch < 7)
            produce_chunk<NA, NB, NC>(ch + 1, hbN, s1, klb, x1, a1, W1, b1);

        #pragma unroll
        for (int ks = 0; ks < 2; ++ks) {
            const int kg = ch * 64 + ks * 32 + kb;
            const half8 A0 = *reinterpret_cast<const half8*>(A0b + kg);
            const half8 A1 = *reinterpret_cast<const half8*>(A1b + kg);
            #pragma unroll
            for (int c = 0; c < NC; ++c) {
                const half8 B = *reinterpret_cast<const half8*>(
                    hfC + (c * 16 + col) * 72 + ks * 32 + kb);
                acc0[c] = __builtin_amdgcn_mfma_f32_16x16x32_f16(A0, B, acc0[c], 0, 0, 0);
                acc1[c] = __builtin_amdgcn_mfma_f32_16x16x32_f16(A1, B, acc1[c], 0, 0, 0);
            }
        }
        __syncthreads();
    }

    // ---------------- layer-2 activation (lane-local, in place) ------------
    // lane holds n2 = tile*16 + rgrp*4 + r for tiles {2w, 2w+1}, sample = col.
    {
        const float* b2p0 = b2 + (2 * w) * 16 + rgrp * 4;
        const float* b2p1 = b2 + (2 * w + 1) * 16 + rgrp * 4;
        #pragma unroll
        for (int r = 0; r < 4; ++r) {
            {
                float pj[NA], qj[NB], yj[NA], rj[NB];
                #pragma unroll
                for (int j = 0; j < NA; ++j) pj[j] = acc0[2 * j][r];
                #pragma unroll
                for (int j = 0; j < NB; ++j) qj[j] = acc0[2 * j + 1][r];
                pj[0] += b2p0[r];
                tanh_jet<NA, NB>(pj, qj, yj, rj);
                #pragma unroll
                for (int j = 0; j < NA; ++j) acc0[2 * j][r] = yj[j];
                #pragma unroll
                for (int j = 0; j < NB; ++j) acc0[2 * j + 1][r] = rj[j];
            }
            {
                float pj[NA], qj[NB], yj[NA], rj[NB];
                #pragma unroll
                for (int j = 0; j < NA; ++j) pj[j] = acc1[2 * j][r];
                #pragma unroll
                for (int j = 0; j < NB; ++j) qj[j] = acc1[2 * j + 1][r];
                pj[0] += b2p1[r];
                tanh_jet<NA, NB>(pj, qj, yj, rj);
                #pragma unroll
                for (int j = 0; j < NA; ++j) acc1[2 * j][r] = yj[j];
                #pragma unroll
                for (int j = 0; j < NB; ++j) acc1[2 * j + 1][r] = rj[j];
            }
        }
    }

    // ---------------- layer 3: two store/mfma passes over K=128 ------------
    f32x4 acc3[NC];
    #pragma unroll
    for (int c = 0; c < NC; ++c) acc3[c] = (f32x4)0.0f;
    const _Float16* A3b = W3t + (w * 16 + col) * 128;

    #pragma unroll
    for (int pass = 0; pass < 2; ++pass) {
        __syncthreads();                     // prior buf0 reads complete
        if ((w >> 1) == pass) {              // waves owning rows [64p,64p+64)
            const int base0 = (w & 1) * 32 + rgrp * 4;        // tile 2w
            const int base1 = base0 + 16;                     // tile 2w+1
            #pragma unroll
            for (int c = 0; c < NC; ++c) {
                hb0[(c * 16 + col) * 36 + (base0 >> 1)]     = pkrtz(acc0[c][0], acc0[c][1]);
                hb0[(c * 16 + col) * 36 + (base0 >> 1) + 1] = pkrtz(acc0[c][2], acc0[c][3]);
                hb0[(c * 16 + col) * 36 + (base1 >> 1)]     = pkrtz(acc1[c][0], acc1[c][1]);
                hb0[(c * 16 + col) * 36 + (base1 >> 1) + 1] = pkrtz(acc1[c][2], acc1[c][3]);
            }
        }
        __syncthreads();
        #pragma unroll
        for (int ks = 0; ks < 2; ++ks) {
            const int kg = pass * 64 + ks * 32 + kb;
            const half8 A3 = *reinterpret_cast<const half8*>(A3b + kg);
            #pragma unroll
            for (int c = 0; c < NC; ++c) {
                const half8 B = *reinterpret_cast<const half8*>(
                    hbuf0 + (c * 16 + col) * 72 + ks * 32 + kb);
                acc3[c] = __builtin_amdgcn_mfma_f32_16x16x32_f16(A3, B, acc3[c], 0, 0, 0);
            }
        }
    }

    // ---------------- layer 4 + loss ----------------
    // lane holds n3 = w*16 + rgrp*4 + r, sample = col.
    float part[NC];
    #pragma unroll
    for (int c = 0; c < NC; ++c) part[c] = 0.0f;
    {
        const float* b3p = b3 + w * 16 + rgrp * 4;
        const float* w4p = W4 + w * 16 + rgrp * 4;
        #pragma unroll
        for (int r = 0; r < 4; ++r) {
            float pj[NA], qj[NB], yj[NA], rj[NB];
            #pragma unroll
            for (int j = 0; j < NA; ++j) pj[j] = acc3[2 * j][r];
            #pragma unroll
            for (int j = 0; j < NB; ++j) qj[j] = acc3[2 * j + 1][r];
            pj[0] += b3p[r];
            tanh_jet<NA, NB>(pj, qj, yj, rj);
            const float w4 = w4p[r];
            #pragma unroll
            for (int c = 0; c < NA; ++c) part[c] = fmaf(w4, yj[c], part[c]);
            #pragma unroll
            for (int c = 0; c < NB; ++c) part[NA + c] = fmaf(w4, rj[c], part[NA + c]);
        }
    }
    // reduce over the 4 row-groups of the wave
    #pragma unroll
    for (int c = 0; c < NC; ++c) {
        part[c] += __shfl_xor(part[c], 16, 64);
        part[c] += __shfl_xor(part[c], 32, 64);
    }
    if (l < 16) {
        #pragma unroll
        for (int c = 0; c < NC; ++c) red[w][l][c] = part[c];
    }
    __syncthreads();

    if (t < 16) {
        float pp[NC];
        #pragma unroll
        for (int c = 0; c < NC; ++c)
            pp[c] = red[0][t][c] + red[1][t][c] + red[2][t][c] + red[3][t][c];
        const int is = bi * 16 + t;
        const bool valid = (is < N);
        const float a_s = inp[2 * ((is < N) ? is : (N - 1)) + 1];
        const float A0v = pp[0] + b4[0];
        float t0 = 0.0f, t1 = 0.0f, t2 = 0.0f;
        constexpr float CC = 1.0f;   // P/(E*I)
        if constexpr (TYPE == 0) {
            const float gx = 6.0f * pp[NA + 3];
            const float ga = 24.0f * pp[4] - gx;
            t0 = (gx + CC) * (gx + CC) + (ga + CC) * (ga + CC);
        }
        if constexpr (TYPE == 1) {
            t0 = A0v * A0v;
            const float gx = pp[NA + 0];
            const float ga = pp[1] - gx;
            t1 = gx * gx + ga * ga;
        }
        if constexpr (TYPE == 2) {
            const float wa = a_s * A0v;
            t0 = wa * wa;
            const float g2x = pp[NA + 1];
            const float g2a = 2.0f * pp[2] - g2x;
            t1 = g2x * g2x + g2a * g2a;
            const float g3x = 2.0f * pp[NA + 2];
            const float g3a = 6.0f * pp[3] - g3x;
            const float om = 1.0f - a_s;
            t2 = om * om * (g3x * g3x + g3a * g3a);
        }
        if (!valid) { t0 = 0.0f; t1 = 0.0f; t2 = 0.0f; }
        #pragma unroll
        for (int m = 1; m <= 8; m <<= 1) {
            t0 += __shfl_xor(t0, m, 64);
            if constexpr (TYPE != 0) t1 += __shfl_xor(t1, m, 64);
            if constexpr (TYPE == 2) t2 += __shfl_xor(t2, m, 64);
        }
        if (t == 0) {
            if constexpr (TYPE == 0) {
                ws[bi] = t0;
            } else if constexpr (TYPE == 1) {
                ws[nbx + bi]     = t0;
                ws[2 * nbx + bi] = t1;
            } else {
                ws[3 * nbx + bi] = t0;
                ws[4 * nbx + bi] = t1;
                ws[5 * nbx + bi] = t2;
            }
        }
    }
}

__global__ __launch_bounds__(256, 2)
void pinn_fat(const float* __restrict__ inp,
              const float* __restrict__ W1, const float* __restrict__ b1,
              const _Float16* __restrict__ W2t, const float* __restrict__ b2,
              const _Float16* __restrict__ W3t, const float* __restrict__ b3,
              const float* __restrict__ W4, const float* __restrict__ b4,
              float* __restrict__ ws, int N, int nbx)
{
    __shared__ __align__(16) _Float16 hbuf0[10368];  // [9][16][72] = 20736 B
    __shared__ __align__(16) _Float16 hbuf1[10368];  // double buffer
    __shared__ float red[4][16][9];                  // 2304 B
    const int b = blockIdx.x;
    if (b < nbx)
        eval_body<5, 4, 0>(b, inp, W1, b1, W2t, b2, W3t, b3, W4, b4, ws, N, nbx, hbuf0, hbuf1, red);
    else if (b < 2 * nbx)
        eval_body<4, 3, 2>(b - nbx, inp, W1, b1, W2t, b2, W3t, b3, W4, b4, ws, N, nbx, hbuf0, hbuf1, red);
    else
        eval_body<2, 1, 1>(b - 2 * nbx, inp, W1, b1, W2t, b2, W3t, b3, W4, b4, ws, N, nbx, hbuf0, hbuf1, red);
}

__global__ __launch_bounds__(1024)
void pinn_reduce(const float* __restrict__ ws, float* __restrict__ out,
                 int G, float invN, float inv2N)
{
    __shared__ float sh[16 * 6];
    float s[6];
    #pragma unroll
    for (int q = 0; q < 6; ++q) {
        float acc = 0.0f;
        for (int i = threadIdx.x; i < G; i += 1024) acc += ws[q * G + i];
        #pragma unroll
        for (int m = 1; m <= 32; m <<= 1) acc += __shfl_xor(acc, m, 64);
        s[q] = acc;
    }
    const int wid = threadIdx.x >> 6;
    if ((threadIdx.x & 63) == 0) {
        #pragma unroll
        for (int q = 0; q < 6; ++q) sh[wid * 6 + q] = s[q];
    }
    __syncthreads();
    if (threadIdx.x == 0) {
        float r[6];
        #pragma unroll
        for (int q = 0; q < 6; ++q) {
            float acc = 0.0f;
            for (int w = 0; w < 16; ++w) acc += sh[w * 6 + q];
            r[q] = acc;
        }
        const float pde   = r[0] * inv2N;
        const float w0    = r[1] * invN;
        const float w0x   = r[2] * inv2N;
        const float wL    = r[3] * invN;
        const float wLxx  = r[4] * inv2N;
        const float wLxxx = r[5] * inv2N;
        out[0] = pde + w0 + w0x + wL + wLxx + wLxxx;
        out[1] = pde;
        out[2] = w0;
        out[3] = w0x;
        out[4] = wL;
        out[5] = wLxx;
        out[6] = wLxxx;
    }
}

extern "C" void kernel_launch(void* const* d_in, const int* in_sizes, int n_in,
                              void* d_out, int out_size, void* d_ws, size_t ws_size,
                              hipStream_t stream) {
    const float* inp = (const float*)d_in[0];
    const float* W1  = (const float*)d_in[1];
    const float* b1  = (const float*)d_in[2];
    const float* W2  = (const float*)d_in[3];
    const float* b2  = (const float*)d_in[4];
    const float* W3  = (const float*)d_in[5];
    const float* b3  = (const float*)d_in[6];
    const float* W4  = (const float*)d_in[7];
    const float* b4  = (const float*)d_in[8];
    float* ws  = (float*)d_ws;
    _Float16* wsh = (_Float16*)d_ws;
    float* out = (float*)d_out;

    const int N   = in_sizes[0] / 2;   // 32768
    const int nbx = (N + 15) / 16;     // blocks per eval type (16 samples/block)

    // transpose + fp16 weights into ws (bytes 65536..212992)
    pinn_prep<<<dim3(256), dim3(256), 0, stream>>>(W2, W3, wsh);

    pinn_fat<<<dim3(3 * nbx), dim3(256), 0, stream>>>(
        inp, W1, b1, wsh + W2T_HOFF, b2, wsh + W3T_HOFF, b3, W4, b4, ws, N, nbx);
    pinn_reduce<<<dim3(1), dim3(1024), 0, stream>>>(
        ws, out, nbx, 1.0f / (float)N, 0.5f / (float)N);
}